// Round 10
// baseline (724.830 us; speedup 1.0000x reference)
//
#include <hip/hip_runtime.h>
#include <math.h>

#define Bsz 4
#define Cch 256
#define Npt 2048
#define Hh  4
#define NL  4
#define BN_CNT (Bsz * Npt)   // 8192
#define EPSV 1e-5f
#define NROW (16 * Npt)      // 32768 attention rows total (bh * Npt)
#define L2E 1.44269504f
#define NIC 8                // i-chunk partials in attention pass B

typedef _Float16 f16x8 __attribute__((ext_vector_type(8)));
typedef _Float16 f16x4 __attribute__((ext_vector_type(4)));
typedef float    f32x4 __attribute__((ext_vector_type(4)));

__device__ __forceinline__ float fexp2(float x) { return __builtin_amdgcn_exp2f(x); }

// async global->LDS, 16B per lane
__device__ __forceinline__ void gld16(const _Float16* g, _Float16* l) {
    __builtin_amdgcn_global_load_lds(
        (const __attribute__((address_space(1))) unsigned int*)g,
        (__attribute__((address_space(3))) unsigned int*)l, 16, 0, 0);
}

// ---------------- xyz embedding ----------------
__global__ void k_xyz_emb(const float* __restrict__ xyz, const float* __restrict__ pw,
                          const float* __restrict__ pb, float* __restrict__ emb) {
    int idx = blockIdx.x * 256 + threadIdx.x;
    int n = idx & (Npt - 1);
    int c = (idx >> 11) & (Cch - 1);
    int b = idx >> 19;
    const float* xz = xyz + (b * Npt + n) * 3;
    emb[idx] = pw[c * 3 + 0] * xz[0] + pw[c * 3 + 1] * xz[1] + pw[c * 3 + 2] * xz[2] + pb[c];
}

// ---------------- cast all weights to fp16; zero BN accumulators ----------------
__global__ void k_castw(const float* __restrict__ c1w, const float* __restrict__ qkw,
                        const float* __restrict__ vw, const float* __restrict__ tw,
                        _Float16* __restrict__ o, float* __restrict__ bnacc) {
    int i = blockIdx.x * 256 + threadIdx.x;
    if (i < 5 * 512) bnacc[i] = 0.f;     // 5 slots x (sum[256], sum2[256])
    const float* src; int off;
    if (i < 65536)            { src = c1w; off = i; }
    else if (i < 327680)      { src = qkw; off = i - 65536; }
    else if (i < 589824)      { src = vw;  off = i - 327680; }
    else                      { src = tw;  off = i - 589824; }
    o[i] = (_Float16)src[off];
}

// ---------------- transpose + cast x -> XT[b][n][c] (entry only) ----------------
__global__ __launch_bounds__(256) void k_fuse_t(const float* __restrict__ in,
        _Float16* __restrict__ XT) {
    __shared__ _Float16 Tt[64][72];
    const int b = blockIdx.z, c0 = blockIdx.y * 64, n0 = blockIdx.x * 64;
    const int t = threadIdx.x;
    const int cl = t >> 2, ns = (t & 3) * 16;
    const float* ip = in + ((size_t)(b * Cch + c0 + cl) * Npt) + n0 + ns;
    #pragma unroll
    for (int g = 0; g < 4; ++g) {
        float4 v = *(const float4*)(ip + g * 4);
        Tt[ns + g * 4 + 0][cl] = (_Float16)v.x;
        Tt[ns + g * 4 + 1][cl] = (_Float16)v.y;
        Tt[ns + g * 4 + 2][cl] = (_Float16)v.z;
        Tt[ns + g * 4 + 3][cl] = (_Float16)v.w;
    }
    __syncthreads();
    int nl = t >> 2, cs = (t & 3) * 16;
    _Float16* op = XT + ((size_t)(b * Npt + n0 + nl) * Cch) + c0 + cs;
    #pragma unroll
    for (int g = 0; g < 4; ++g)
        *(f16x4*)(op + g * 4) = *(f16x4*)&Tt[nl][cs + g * 4];
}

// ---------------- MFMA GEMM (fp32 out) + fused BN partial-stat atomics ----------------
__global__ __launch_bounds__(256) void k_gemm_mfma(const _Float16* __restrict__ Wb,
        const _Float16* __restrict__ XT, const float* __restrict__ bias,
        float* __restrict__ Yf, float* __restrict__ bnacc) {
    __shared__ float EpF[64][68];
    const int b = blockIdx.z, o0 = blockIdx.y * 64, n0 = blockIdx.x * 64;
    const int tid = threadIdx.x, w = tid >> 6, quad = (tid >> 4) & 3, tx = tid & 15;
    const _Float16* Arow = Wb + (o0 + w * 16 + tx) * Cch + quad * 8;
    const _Float16* Brow = XT + ((size_t)(b * Npt + n0 + tx) * Cch) + quad * 8;
    f32x4 acc[4];
    #pragma unroll
    for (int s = 0; s < 4; ++s) acc[s] = (f32x4){0.f, 0.f, 0.f, 0.f};
    for (int k0 = 0; k0 < Cch; k0 += 32) {
        f16x8 a = *(const f16x8*)(Arow + k0);
        #pragma unroll
        for (int s = 0; s < 4; ++s) {
            f16x8 bb = *(const f16x8*)(Brow + s * 16 * Cch + k0);
            acc[s] = __builtin_amdgcn_mfma_f32_16x16x32_f16(a, bb, acc[s], 0, 0, 0);
        }
    }
    float bv[4];
    {
        int ob = o0 + w * 16 + quad * 4;
        if (bias) { bv[0] = bias[ob]; bv[1] = bias[ob + 1]; bv[2] = bias[ob + 2]; bv[3] = bias[ob + 3]; }
        else bv[0] = bv[1] = bv[2] = bv[3] = 0.f;
    }
    #pragma unroll
    for (int s = 0; s < 4; ++s) {
        int ol = w * 16 + quad * 4, nl = s * 16 + tx;
        EpF[ol + 0][nl] = acc[s][0] + bv[0];
        EpF[ol + 1][nl] = acc[s][1] + bv[1];
        EpF[ol + 2][nl] = acc[s][2] + bv[2];
        EpF[ol + 3][nl] = acc[s][3] + bv[3];
    }
    __syncthreads();
    int row = tid >> 2, seg = (tid & 3) * 16;
    float* yp = Yf + ((size_t)(b * Cch + o0 + row) * Npt) + n0 + seg;
    float s1 = 0.f, s2 = 0.f;
    #pragma unroll
    for (int g = 0; g < 4; ++g) {
        float4 v = *(float4*)&EpF[row][seg + g * 4];
        *(float4*)(yp + g * 4) = v;
        s1 += v.x + v.y + v.z + v.w;
        s2 += v.x * v.x + v.y * v.y + v.z * v.z + v.w * v.w;
    }
    s1 += __shfl_xor(s1, 1); s2 += __shfl_xor(s2, 1);
    s1 += __shfl_xor(s1, 2); s2 += __shfl_xor(s2, 2);
    if ((tid & 3) == 0) {
        atomicAdd(&bnacc[o0 + row], s1);
        atomicAdd(&bnacc[256 + o0 + row], s2);
    }
}

// ---------------- fused qk + v GEMM: y<4 -> Qg/Kt (swizzled), y>=4 -> Vb fp16 ----------------
__global__ __launch_bounds__(256) void k_gemm_qkv(const _Float16* __restrict__ Wqk,
        const _Float16* __restrict__ Wv, const _Float16* __restrict__ XT,
        const float* __restrict__ vbias, _Float16* __restrict__ Vb,
        _Float16* __restrict__ Qg, _Float16* __restrict__ Kt) {
    __shared__ _Float16 EpB[64][72];
    const int b = blockIdx.z, y = blockIdx.y, n0 = blockIdx.x * 64;
    const int isV = (y >= 4);
    const int o0 = (isV ? (y - 4) : y) * 64;
    const _Float16* Wb = isV ? Wv : Wqk;
    const int tid = threadIdx.x, w = tid >> 6, quad = (tid >> 4) & 3, tx = tid & 15;
    const _Float16* Arow = Wb + (o0 + w * 16 + tx) * Cch + quad * 8;
    const _Float16* Brow = XT + ((size_t)(b * Npt + n0 + tx) * Cch) + quad * 8;
    f32x4 acc[4];
    #pragma unroll
    for (int s = 0; s < 4; ++s) acc[s] = (f32x4){0.f, 0.f, 0.f, 0.f};
    for (int k0 = 0; k0 < Cch; k0 += 32) {
        f16x8 a = *(const f16x8*)(Arow + k0);
        #pragma unroll
        for (int s = 0; s < 4; ++s) {
            f16x8 bb = *(const f16x8*)(Brow + s * 16 * Cch + k0);
            acc[s] = __builtin_amdgcn_mfma_f32_16x16x32_f16(a, bb, acc[s], 0, 0, 0);
        }
    }
    if (!isV) {
        const int cch = (w << 1) + (quad >> 1);
        const int hof = (quad & 1) * 4;
        #pragma unroll
        for (int s = 0; s < 4; ++s) {
            int ng = n0 + s * 16 + tx;
            f16x4 pk;
            pk[0] = (_Float16)acc[s][0]; pk[1] = (_Float16)acc[s][1];
            pk[2] = (_Float16)acc[s][2]; pk[3] = (_Float16)acc[s][3];
            int rK = ng & 63, jt = ng >> 6;
            size_t ka = ((size_t)((b * Hh + (o0 >> 6)) * 32 + jt) << 12)
                      + rK * 64 + ((cch ^ (rK & 7)) * 8) + hof;
            *(f16x4*)&Kt[ka] = pk;
            int iQ = ((ng & 511) << 2) + (o0 >> 6);
            int rQ = iQ & 63, it = iQ >> 6;
            size_t qa = ((size_t)((b * Hh + (ng >> 9)) * 32 + it) << 12)
                      + rQ * 64 + ((cch ^ (rQ & 7)) * 8) + hof;
            *(f16x4*)&Qg[qa] = pk;
        }
        return;
    }
    float bv[4];
    {
        int ob = o0 + w * 16 + quad * 4;
        bv[0] = vbias[ob]; bv[1] = vbias[ob + 1]; bv[2] = vbias[ob + 2]; bv[3] = vbias[ob + 3];
    }
    #pragma unroll
    for (int s = 0; s < 4; ++s) {
        int ol = w * 16 + quad * 4, nl = s * 16 + tx;
        EpB[ol + 0][nl] = (_Float16)(acc[s][0] + bv[0]);
        EpB[ol + 1][nl] = (_Float16)(acc[s][1] + bv[1]);
        EpB[ol + 2][nl] = (_Float16)(acc[s][2] + bv[2]);
        EpB[ol + 3][nl] = (_Float16)(acc[s][3] + bv[3]);
    }
    __syncthreads();
    int row = tid >> 2, seg = (tid & 3) * 16;
    _Float16* yp = Vb + ((size_t)(b * Cch + o0 + row) * Npt) + n0 + seg;
    #pragma unroll
    for (int g = 0; g < 4; ++g)
        *(f16x4*)(yp + g * 4) = *(f16x4*)&EpB[row][seg + g * 4];
}

// ---------------- attention pass A: 128 i-rows/block, per-lane online (m2,l) ----------------
__global__ __launch_bounds__(256) void k_attn_A(const _Float16* __restrict__ Qg,
        const _Float16* __restrict__ Kt, float* __restrict__ mP, float* __restrict__ lP) {
    __shared__ _Float16 Ksh[2][4096];
    const int bh = blockIdx.z, jc = blockIdx.y, i0 = blockIdx.x * 128;
    const int tid = threadIdx.x, w = tid >> 6, q = (tid >> 4) & 3, tx = tid & 15;
    const int lane = tid & 63;
    const int sx = tx & 7;
    f16x8 qa[2][2];
    #pragma unroll
    for (int g = 0; g < 2; ++g) {
        const _Float16* Qtile = Qg + ((size_t)(bh * 32 + ((i0 + g * 64) >> 6)) << 12);
        int r = w * 16 + tx;
        qa[g][0] = *(const f16x8*)(Qtile + r * 64 + (q ^ sx) * 8);
        qa[g][1] = *(const f16x8*)(Qtile + r * 64 + ((q + 4) ^ sx) * 8);
    }
    const _Float16* Kbase = Kt + ((size_t)(bh * 32) << 12);
    const int jt0 = jc * 8;
    {
        const _Float16* g = Kbase + ((size_t)jt0 << 12) + (w * 2) * 512 + lane * 8;
        gld16(g,       &Ksh[0][(w * 2 + 0) * 512]);
        gld16(g + 512, &Ksh[0][(w * 2 + 1) * 512]);
    }
    __syncthreads();
    float m2[2][4], l[2][4];
    #pragma unroll
    for (int g = 0; g < 2; ++g)
        #pragma unroll
        for (int r = 0; r < 4; ++r) { m2[g][r] = -1e30f; l[g][r] = 0.f; }
    for (int t = 0; t < 8; ++t) {
        if (t < 7) {
            const _Float16* g = Kbase + ((size_t)(jt0 + t + 1) << 12) + (w * 2) * 512 + lane * 8;
            gld16(g,       &Ksh[(t + 1) & 1][(w * 2 + 0) * 512]);
            gld16(g + 512, &Ksh[(t + 1) & 1][(w * 2 + 1) * 512]);
        }
        const _Float16* kbuf = Ksh[t & 1];
        f32x4 e[2][4];
        #pragma unroll
        for (int s = 0; s < 4; ++s) {
            int r = s * 16 + tx;
            f16x8 kb0 = *(const f16x8*)(kbuf + r * 64 + (q ^ sx) * 8);
            f16x8 kb1 = *(const f16x8*)(kbuf + r * 64 + ((q + 4) ^ sx) * 8);
            #pragma unroll
            for (int g = 0; g < 2; ++g) {
                f32x4 z = (f32x4){0.f, 0.f, 0.f, 0.f};
                z = __builtin_amdgcn_mfma_f32_16x16x32_f16(qa[g][0], kb0, z, 0, 0, 0);
                e[g][s] = __builtin_amdgcn_mfma_f32_16x16x32_f16(qa[g][1], kb1, z, 0, 0, 0);
            }
        }
        #pragma unroll
        for (int g = 0; g < 2; ++g)
            #pragma unroll
            for (int r = 0; r < 4; ++r) {
                float e0 = e[g][0][r] * L2E, e1 = e[g][1][r] * L2E;
                float e2 = e[g][2][r] * L2E, e3 = e[g][3][r] * L2E;
                float lm = fmaxf(fmaxf(e0, e1), fmaxf(e2, e3));
                float nm = fmaxf(m2[g][r], lm);
                l[g][r] = l[g][r] * fexp2(m2[g][r] - nm)
                        + fexp2(e0 - nm) + fexp2(e1 - nm) + fexp2(e2 - nm) + fexp2(e3 - nm);
                m2[g][r] = nm;
            }
        __syncthreads();
    }
    #pragma unroll
    for (int g = 0; g < 2; ++g)
        #pragma unroll
        for (int r = 0; r < 4; ++r) {
            float mm = m2[g][r], ll = l[g][r];
            #pragma unroll
            for (int off = 1; off < 16; off <<= 1) {
                float om = __shfl_xor(mm, off), ol = __shfl_xor(ll, off);
                float nm = fmaxf(mm, om);
                ll = ll * fexp2(mm - nm) + ol * fexp2(om - nm);
                mm = nm;
            }
            if (tx == 0) {
                int idx = bh * Npt + i0 + g * 64 + w * 16 + q * 4 + r;
                mP[jc * NROW + idx] = mm;
                lP[jc * NROW + idx] = ll;
            }
        }
}

// ---------------- combine chunk (m2,l) partials -> rowm2, rowli2 = L2E/l ----------------
__global__ void k_mlcomb(const float* __restrict__ mP, const float* __restrict__ lP,
                         float* __restrict__ rowm2, float* __restrict__ rowli2) {
    int row = blockIdx.x * 256 + threadIdx.x;    // NROW threads
    float m0 = mP[row], m1 = mP[NROW + row], m2 = mP[2 * NROW + row], m3 = mP[3 * NROW + row];
    float m = fmaxf(fmaxf(m0, m1), fmaxf(m2, m3));
    float l = lP[row] * fexp2(m0 - m) + lP[NROW + row] * fexp2(m1 - m)
            + lP[2 * NROW + row] * fexp2(m2 - m) + lP[3 * NROW + row] * fexp2(m3 - m);
    rowm2[row] = m;
    rowli2[row] = L2E / l;
}

// ---------------- attention pass B: wave-private 256-row i-chunks, zero barriers ----------------
// grid (32 j-tiles, 2 ic2, 16 bh) = 1024 blocks (4 blocks/CU). Wave w owns i-chunk
// ip=ic2*4+w (256 rows) x all 64 j. #pragma unroll 1 on the it loop keeps VGPR ~96
// (round-8 lesson: auto-unroll of a 4-iter loop ballooned live state to 156 VGPR).
__global__ __launch_bounds__(256) void k_attn_B(const _Float16* __restrict__ Qg,
        const _Float16* __restrict__ Kt, const _Float16* __restrict__ Vb,
        const float* __restrict__ rowm2, const float* __restrict__ rowli2,
        _Float16* __restrict__ Tp, float* __restrict__ Sp) {
    __shared__ _Float16 AtT[4][4096];     // per-wave 8KB swizzled P scratch
    const int bh = blockIdx.z, ic2 = blockIdx.y, j0 = blockIdx.x * 64;
    const int b = bh >> 2, hd = bh & 3;
    const int tid = threadIdx.x, w = tid >> 6, q = (tid >> 4) & 3, tx = tid & 15;
    const int sx = tx & 7;
    const int ip = ic2 * 4 + w;           // partial index 0..7
    f16x8 kb[4][2];
    const _Float16* Ktile = Kt + ((size_t)(bh * 32 + (j0 >> 6)) << 12);
    #pragma unroll
    for (int nt = 0; nt < 4; ++nt) {
        int r = nt * 16 + tx;
        kb[nt][0] = *(const f16x8*)(Ktile + r * 64 + (q ^ sx) * 8);
        kb[nt][1] = *(const f16x8*)(Ktile + r * 64 + ((q + 4) ^ sx) * 8);
    }
    f32x4 Tacc[4][4];
    #pragma unroll
    for (int mt = 0; mt < 4; ++mt)
        #pragma unroll
        for (int nt = 0; nt < 4; ++nt) Tacc[mt][nt] = (f32x4){0.f, 0.f, 0.f, 0.f};
    float scS[4] = {0.f, 0.f, 0.f, 0.f};
    _Float16* myAt = AtT[w];
    const _Float16* vbase = Vb + (size_t)(b * Cch + hd * 64) * Npt;
    const float* m2b = rowm2 + bh * Npt;
    const float* lib = rowli2 + bh * Npt;
    #pragma unroll 1
    for (int it = 0; it < 4; ++it) {
        const int i0 = ip * 256 + it * 64;
        const _Float16* Qtile = Qg + ((size_t)(bh * 32 + (i0 >> 6)) << 12);
        #pragma unroll
        for (int mt = 0; mt < 4; ++mt) {
            int r = mt * 16 + tx;
            f16x8 qa0 = *(const f16x8*)(Qtile + r * 64 + (q ^ sx) * 8);
            f16x8 qa1 = *(const f16x8*)(Qtile + r * 64 + ((q + 4) ^ sx) * 8);
            float4 m2v = *(const float4*)(m2b + i0 + mt * 16 + q * 4);
            float4 liv = *(const float4*)(lib + i0 + mt * 16 + q * 4);
            #pragma unroll
            for (int nt = 0; nt < 4; ++nt) {
                f32x4 z = (f32x4){0.f, 0.f, 0.f, 0.f};
                z = __builtin_amdgcn_mfma_f32_16x16x32_f16(qa0, kb[nt][0], z, 0, 0, 0);
                z = __builtin_amdgcn_mfma_f32_16x16x32_f16(qa1, kb[nt][1], z, 0, 0, 0);
                float a0 = fexp2(fexp2(__builtin_fmaf(z[0], L2E, -m2v.x)) * liv.x);
                float a1 = fexp2(fexp2(__builtin_fmaf(z[1], L2E, -m2v.y)) * liv.y);
                float a2 = fexp2(fexp2(__builtin_fmaf(z[2], L2E, -m2v.z)) * liv.z);
                float a3 = fexp2(fexp2(__builtin_fmaf(z[3], L2E, -m2v.w)) * liv.w);
                scS[nt] += a0 + a1 + a2 + a3;
                f16x4 pk;
                pk[0] = (_Float16)a0; pk[1] = (_Float16)a1;
                pk[2] = (_Float16)a2; pk[3] = (_Float16)a3;
                *(f16x4*)&myAt[(nt * 16 + tx) * 64 + ((2 * mt + (q >> 1)) ^ sx) * 8 + (q & 1) * 4] = pk;
            }
        }
        f16x8 pb[4][2], va[4][2];
        #pragma unroll
        for (int nt = 0; nt < 4; ++nt) {
            int r = nt * 16 + tx;
            pb[nt][0] = *(const f16x8*)&myAt[r * 64 + (q ^ sx) * 8];
            pb[nt][1] = *(const f16x8*)&myAt[r * 64 + ((q + 4) ^ sx) * 8];
        }
        #pragma unroll
        for (int mt = 0; mt < 4; ++mt) {
            const _Float16* vp = vbase + (size_t)(mt * 16 + tx) * Npt + i0 + q * 8;
            va[mt][0] = *(const f16x8*)(vp);
            va[mt][1] = *(const f16x8*)(vp + 32);
        }
        #pragma unroll
        for (int mt = 0; mt < 4; ++mt)
            #pragma unroll
            for (int nt = 0; nt < 4; ++nt) {
                Tacc[mt][nt] = __builtin_amdgcn_mfma_f32_16x16x32_f16(va[mt][0], pb[nt][0], Tacc[mt][nt], 0, 0, 0);
                Tacc[mt][nt] = __builtin_amdgcn_mfma_f32_16x16x32_f16(va[mt][1], pb[nt][1], Tacc[mt][nt], 0, 0, 0);
            }
    }
    const size_t NE = (size_t)Bsz * Cch * Npt;
    #pragma unroll
    for (int mt = 0; mt < 4; ++mt)
        #pragma unroll
        for (int nt = 0; nt < 4; ++nt) {
            int d = hd * 64 + mt * 16 + q * 4;
            int jg = j0 + nt * 16 + tx;
            _Float16* tp = Tp + (size_t)ip * NE + (size_t)(b * Cch + d) * Npt + jg;
            tp[0 * Npt] = (_Float16)Tacc[mt][nt][0];
            tp[1 * Npt] = (_Float16)Tacc[mt][nt][1];
            tp[2 * Npt] = (_Float16)Tacc[mt][nt][2];
            tp[3 * Npt] = (_Float16)Tacc[mt][nt][3];
        }
    #pragma unroll
    for (int nt = 0; nt < 4; ++nt) {
        float s = scS[nt];
        s += __shfl_xor(s, 16);
        s += __shfl_xor(s, 32);
        if (q == 0) Sp[(size_t)ip * NROW + bh * Npt + j0 + nt * 16 + tx] = s;
    }
}

// ---------------- reduce T/S partials (8), u = h - T/S, transpose+cast -> XT ----------------
__global__ __launch_bounds__(256) void k_redT_fuse(const float* __restrict__ h,
        const _Float16* __restrict__ Tp, const float* __restrict__ Sp,
        _Float16* __restrict__ XT) {
    __shared__ _Float16 Tt[64][72];
    __shared__ float rsL[64];
    const int b = blockIdx.z, c0 = blockIdx.y * 64, n0 = blockIdx.x * 64;
    const int t = threadIdx.x;
    const int bh = b * Hh + (c0 >> 6);
    if (t < 64) {
        float s = 0.f;
        #pragma unroll
        for (int ic = 0; ic < NIC; ++ic) s += Sp[(size_t)ic * NROW + bh * Npt + n0 + t];
        rsL[t] = 1.f / s;
    }
    __syncthreads();
    const int cl = t >> 2, ns = (t & 3) * 16;
    const size_t NE = (size_t)Bsz * Cch * Npt;
    const size_t rowoff = ((size_t)(b * Cch + c0 + cl) * Npt) + n0 + ns;
    float tv[16];
    #pragma unroll
    for (int e = 0; e < 16; ++e) tv[e] = 0.f;
    #pragma unroll
    for (int ic = 0; ic < NIC; ++ic) {
        const _Float16* qq = Tp + (size_t)ic * NE + rowoff;
        #pragma unroll
        for (int g = 0; g < 2; ++g) {
            f16x8 vv = *(const f16x8*)(qq + g * 8);
            #pragma unroll
            for (int e = 0; e < 8; ++e) tv[g * 8 + e] += (float)vv[e];
        }
    }
    const float* hp = h + rowoff;
    #pragma unroll
    for (int g = 0; g < 4; ++g) {
        float4 hv = *(const float4*)(hp + g * 4);
        Tt[ns + g * 4 + 0][cl] = (_Float16)(hv.x - tv[g * 4 + 0] * rsL[ns + g * 4 + 0]);
        Tt[ns + g * 4 + 1][cl] = (_Float16)(hv.y - tv[g * 4 + 1] * rsL[ns + g * 4 + 1]);
        Tt[ns + g * 4 + 2][cl] = (_Float16)(hv.z - tv[g * 4 + 2] * rsL[ns + g * 4 + 2]);
        Tt[ns + g * 4 + 3][cl] = (_Float16)(hv.w - tv[g * 4 + 3] * rsL[ns + g * 4 + 3]);
    }
    __syncthreads();
    int nl = t >> 2, cs = (t & 3) * 16;
    _Float16* op = XT + ((size_t)(b * Npt + n0 + nl) * Cch) + c0 + cs;
    #pragma unroll
    for (int g = 0; g < 4; ++g)
        *(f16x4*)(op + g * 4) = *(f16x4*)&Tt[nl][cs + g * 4];
}

// ---- fused BN(from atomically-accumulated stats) + relu + residual + out + transpose -> XT ----
__global__ __launch_bounds__(256) void k_bn_fuse(const float* __restrict__ t,
        const float* __restrict__ bnacc,
        const float* __restrict__ g, const float* __restrict__ bt,
        const float* __restrict__ emb, const float* __restrict__ resid,
        float* __restrict__ hout, float* __restrict__ out, _Float16* __restrict__ XT,
        int layer) {
    __shared__ _Float16 Tt[64][72];
    const int b = blockIdx.z, c0 = blockIdx.y * 64, n0 = blockIdx.x * 64;
    const int tt = threadIdx.x;
    const int cl = tt >> 2, ns = (tt & 3) * 16;
    const int c = c0 + cl;
    const float mn = bnacc[c] * (1.f / BN_CNT);
    const float var = bnacc[256 + c] * (1.f / BN_CNT) - mn * mn;
    const float is = rsqrtf(var + EPSV);
    const float gg = g[c], bb = bt[c];
    const size_t rowoff = ((size_t)(b * Cch + c) * Npt) + n0 + ns;
    const float* tp = t + rowoff;
    const float* ep = emb + rowoff;
    const float* rp = resid ? resid + rowoff : nullptr;
    float* hp = hout + rowoff;
    float* op = out ? out + (size_t)b * (NL * Cch * Npt) + (size_t)(layer * Cch + c) * Npt + n0 + ns
                    : nullptr;
    #pragma unroll
    for (int gi = 0; gi < 4; ++gi) {
        float4 v = *(const float4*)(tp + gi * 4);
        float4 y;
        y.x = fmaxf(gg * (v.x - mn) * is + bb, 0.f);
        y.y = fmaxf(gg * (v.y - mn) * is + bb, 0.f);
        y.z = fmaxf(gg * (v.z - mn) * is + bb, 0.f);
        y.w = fmaxf(gg * (v.w - mn) * is + bb, 0.f);
        if (rp) {
            float4 r = *(const float4*)(rp + gi * 4);
            y.x += r.x; y.y += r.y; y.z += r.z; y.w += r.w;
        }
        *(float4*)(hp + gi * 4) = y;
        if (op) *(float4*)(op + gi * 4) = y;
        float4 e = *(const float4*)(ep + gi * 4);
        Tt[ns + gi * 4 + 0][cl] = (_Float16)(y.x + e.x);
        Tt[ns + gi * 4 + 1][cl] = (_Float16)(y.y + e.y);
        Tt[ns + gi * 4 + 2][cl] = (_Float16)(y.z + e.z);
        Tt[ns + gi * 4 + 3][cl] = (_Float16)(y.w + e.w);
    }
    __syncthreads();
    int nl = tt >> 2, cs = (tt & 3) * 16;
    _Float16* xp = XT + ((size_t)(b * Npt + n0 + nl) * Cch) + c0 + cs;
    #pragma unroll
    for (int gi = 0; gi < 4; ++gi)
        *(f16x4*)(xp + gi * 4) = *(f16x4*)&Tt[nl][cs + gi * 4];
}

extern "C" void kernel_launch(void* const* d_in, const int* in_sizes, int n_in,
                              void* d_out, int out_size, void* d_ws, size_t ws_size,
                              hipStream_t stream) {
    (void)in_sizes; (void)n_in; (void)out_size; (void)ws_size;
    const float* x    = (const float*)d_in[0];
    const float* xyz  = (const float*)d_in[1];
    const float* c1w  = (const float*)d_in[2];
    const float* posw = (const float*)d_in[3];
    const float* posb = (const float*)d_in[4];
    const float* bn1g = (const float*)d_in[5];
    const float* bn1b = (const float*)d_in[6];
    const float* qkw  = (const float*)d_in[7];
    const float* vw   = (const float*)d_in[8];
    const float* vb   = (const float*)d_in[9];
    const float* tw   = (const float*)d_in[10];
    const float* tb   = (const float*)d_in[11];
    const float* bng  = (const float*)d_in[12];
    const float* bnb  = (const float*)d_in[13];
    float* out = (float*)d_out;

    const size_t NE = (size_t)Bsz * Cch * Npt;   // 2,097,152
    char* W = (char*)d_ws;
    float* emb   = (float*)W;                 W += NE * 4;
    float* h     = (float*)W;                 W += NE * 4;
    float* vbuf  = (float*)W;                 W += NE * 4;   // fp32 conv outputs
    _Float16* Tp = (_Float16*)W;              W += (size_t)NIC * NE * 2;   // 8 fp16 partials (32 MB)
    _Float16* XT = (_Float16*)W;              W += NE * 2;
    _Float16* Qg = (_Float16*)W;              W += NE * 2;
    _Float16* Kt = (_Float16*)W;              W += NE * 2;
    _Float16* Vb = (_Float16*)W;              W += NE * 2;
    _Float16* wbf = (_Float16*)W;             W += 851968 * 2;
    float* rowm2 = (float*)W;                 W += NROW * 4;
    float* rowli2 = (float*)W;                W += NROW * 4;
    float* mP    = (float*)W;                 W += 4 * NROW * 4;
    float* lP    = (float*)W;                 W += 4 * NROW * 4;
    float* Sp    = (float*)W;                 W += NIC * NROW * 4;
    float* bnacc = (float*)W;                 W += 5 * 512 * 4;   // 5 slots x (sum,sum2)

    dim3 blk(256);
    dim3 g4(Npt / 64, Cch / 64, Bsz);    // 32,4,4
    dim3 gQKV(Npt / 64, 8, Bsz);         // 32,8,4 — fused qk+v
    dim3 gA(Npt / 128, 4, 16);           // attention pass A (128 i-rows/block)
    dim3 gB(Npt / 64, 2, 16);            // attention pass B (1024 blocks, 8 i-chunks)
    int ew = (int)(NE / 256);

    k_castw<<<3328, blk, 0, stream>>>(c1w, qkw, vw, tw, wbf, bnacc);
    k_xyz_emb<<<ew, blk, 0, stream>>>(xyz, posw, posb, emb);

    // h0 = relu(bn1(conv1_w @ x)); XT = transpose(h0 + emb)
    k_fuse_t<<<g4, blk, 0, stream>>>(x, XT);
    k_gemm_mfma<<<g4, blk, 0, stream>>>(wbf, XT, nullptr, vbuf, bnacc);
    k_bn_fuse<<<g4, blk, 0, stream>>>(vbuf, bnacc, bn1g, bn1b, emb, nullptr,
                                      h, nullptr, XT, 0);

    for (int L = 0; L < NL; ++L) {
        const _Float16* qkL = wbf + 65536 + (size_t)L * 65536;
        const _Float16* vL  = wbf + 327680 + (size_t)L * 65536;
        const _Float16* tL  = wbf + 589824 + (size_t)L * 65536;
        float* accL = bnacc + (1 + L) * 512;
        k_gemm_qkv<<<gQKV, blk, 0, stream>>>(qkL, vL, XT, vb + L * Cch, Vb, Qg, Kt);
        k_attn_A<<<gA, blk, 0, stream>>>(Qg, Kt, mP, lP);
        k_mlcomb<<<NROW / 256, blk, 0, stream>>>(mP, lP, rowm2, rowli2);
        k_attn_B<<<gB, blk, 0, stream>>>(Qg, Kt, Vb, rowm2, rowli2, Tp, Sp);
        k_redT_fuse<<<g4, blk, 0, stream>>>(h, Tp, Sp, XT);
        k_gemm_mfma<<<g4, blk, 0, stream>>>(tL, XT, tb + L * Cch, vbuf, accL);
        k_bn_fuse<<<g4, blk, 0, stream>>>(vbuf, accL, bng + L * Cch, bnb + L * Cch,
                                          emb, h, h, out, XT, L);
    }
}

// Round 11
// 671.713 us; speedup vs baseline: 1.0791x; 1.0791x over previous
//
#include <hip/hip_runtime.h>
#include <math.h>

#define Bsz 4
#define Cch 256
#define Npt 2048
#define Hh  4
#define NL  4
#define BN_CNT (Bsz * Npt)   // 8192
#define EPSV 1e-5f
#define NROW (16 * Npt)      // 32768 attention rows total (bh * Npt)
#define L2E 1.44269504f
#define NIC 4                // i-chunk partials in attention pass B (== waves/block)

typedef _Float16 f16x8 __attribute__((ext_vector_type(8)));
typedef _Float16 f16x4 __attribute__((ext_vector_type(4)));
typedef float    f32x4 __attribute__((ext_vector_type(4)));

__device__ __forceinline__ float fexp2(float x) { return __builtin_amdgcn_exp2f(x); }

// async global->LDS, 16B per lane
__device__ __forceinline__ void gld16(const _Float16* g, _Float16* l) {
    __builtin_amdgcn_global_load_lds(
        (const __attribute__((address_space(1))) unsigned int*)g,
        (__attribute__((address_space(3))) unsigned int*)l, 16, 0, 0);
}

// ---------------- xyz embedding ----------------
__global__ void k_xyz_emb(const float* __restrict__ xyz, const float* __restrict__ pw,
                          const float* __restrict__ pb, float* __restrict__ emb) {
    int idx = blockIdx.x * 256 + threadIdx.x;
    int n = idx & (Npt - 1);
    int c = (idx >> 11) & (Cch - 1);
    int b = idx >> 19;
    const float* xz = xyz + (b * Npt + n) * 3;
    emb[idx] = pw[c * 3 + 0] * xz[0] + pw[c * 3 + 1] * xz[1] + pw[c * 3 + 2] * xz[2] + pb[c];
}

// ---------------- cast all weights to fp16; zero BN accumulators ----------------
__global__ void k_castw(const float* __restrict__ c1w, const float* __restrict__ qkw,
                        const float* __restrict__ vw, const float* __restrict__ tw,
                        _Float16* __restrict__ o, float* __restrict__ bnacc) {
    int i = blockIdx.x * 256 + threadIdx.x;
    if (i < 5 * 512) bnacc[i] = 0.f;     // 5 slots x (sum[256], sum2[256])
    const float* src; int off;
    if (i < 65536)            { src = c1w; off = i; }
    else if (i < 327680)      { src = qkw; off = i - 65536; }
    else if (i < 589824)      { src = vw;  off = i - 327680; }
    else                      { src = tw;  off = i - 589824; }
    o[i] = (_Float16)src[off];
}

// ---------------- transpose + cast x -> XT[b][n][c] (entry only) ----------------
__global__ __launch_bounds__(256) void k_fuse_t(const float* __restrict__ in,
        _Float16* __restrict__ XT) {
    __shared__ _Float16 Tt[64][72];
    const int b = blockIdx.z, c0 = blockIdx.y * 64, n0 = blockIdx.x * 64;
    const int t = threadIdx.x;
    const int cl = t >> 2, ns = (t & 3) * 16;
    const float* ip = in + ((size_t)(b * Cch + c0 + cl) * Npt) + n0 + ns;
    #pragma unroll
    for (int g = 0; g < 4; ++g) {
        float4 v = *(const float4*)(ip + g * 4);
        Tt[ns + g * 4 + 0][cl] = (_Float16)v.x;
        Tt[ns + g * 4 + 1][cl] = (_Float16)v.y;
        Tt[ns + g * 4 + 2][cl] = (_Float16)v.z;
        Tt[ns + g * 4 + 3][cl] = (_Float16)v.w;
    }
    __syncthreads();
    int nl = t >> 2, cs = (t & 3) * 16;
    _Float16* op = XT + ((size_t)(b * Npt + n0 + nl) * Cch) + c0 + cs;
    #pragma unroll
    for (int g = 0; g < 4; ++g)
        *(f16x4*)(op + g * 4) = *(f16x4*)&Tt[nl][cs + g * 4];
}

// ---------------- MFMA GEMM (fp32 out) + fused BN partial-stat atomics ----------------
__global__ __launch_bounds__(256) void k_gemm_mfma(const _Float16* __restrict__ Wb,
        const _Float16* __restrict__ XT, const float* __restrict__ bias,
        float* __restrict__ Yf, float* __restrict__ bnacc) {
    __shared__ float EpF[64][68];
    const int b = blockIdx.z, o0 = blockIdx.y * 64, n0 = blockIdx.x * 64;
    const int tid = threadIdx.x, w = tid >> 6, quad = (tid >> 4) & 3, tx = tid & 15;
    const _Float16* Arow = Wb + (o0 + w * 16 + tx) * Cch + quad * 8;
    const _Float16* Brow = XT + ((size_t)(b * Npt + n0 + tx) * Cch) + quad * 8;
    f32x4 acc[4];
    #pragma unroll
    for (int s = 0; s < 4; ++s) acc[s] = (f32x4){0.f, 0.f, 0.f, 0.f};
    for (int k0 = 0; k0 < Cch; k0 += 32) {
        f16x8 a = *(const f16x8*)(Arow + k0);
        #pragma unroll
        for (int s = 0; s < 4; ++s) {
            f16x8 bb = *(const f16x8*)(Brow + s * 16 * Cch + k0);
            acc[s] = __builtin_amdgcn_mfma_f32_16x16x32_f16(a, bb, acc[s], 0, 0, 0);
        }
    }
    float bv[4];
    {
        int ob = o0 + w * 16 + quad * 4;
        if (bias) { bv[0] = bias[ob]; bv[1] = bias[ob + 1]; bv[2] = bias[ob + 2]; bv[3] = bias[ob + 3]; }
        else bv[0] = bv[1] = bv[2] = bv[3] = 0.f;
    }
    #pragma unroll
    for (int s = 0; s < 4; ++s) {
        int ol = w * 16 + quad * 4, nl = s * 16 + tx;
        EpF[ol + 0][nl] = acc[s][0] + bv[0];
        EpF[ol + 1][nl] = acc[s][1] + bv[1];
        EpF[ol + 2][nl] = acc[s][2] + bv[2];
        EpF[ol + 3][nl] = acc[s][3] + bv[3];
    }
    __syncthreads();
    int row = tid >> 2, seg = (tid & 3) * 16;
    float* yp = Yf + ((size_t)(b * Cch + o0 + row) * Npt) + n0 + seg;
    float s1 = 0.f, s2 = 0.f;
    #pragma unroll
    for (int g = 0; g < 4; ++g) {
        float4 v = *(float4*)&EpF[row][seg + g * 4];
        *(float4*)(yp + g * 4) = v;
        s1 += v.x + v.y + v.z + v.w;
        s2 += v.x * v.x + v.y * v.y + v.z * v.z + v.w * v.w;
    }
    s1 += __shfl_xor(s1, 1); s2 += __shfl_xor(s2, 1);
    s1 += __shfl_xor(s1, 2); s2 += __shfl_xor(s2, 2);
    if ((tid & 3) == 0) {
        atomicAdd(&bnacc[o0 + row], s1);
        atomicAdd(&bnacc[256 + o0 + row], s2);
    }
}

// ---------------- fused qk + v GEMM: y<4 -> Qg/Kt (swizzled), y>=4 -> Vb fp16 ----------------
__global__ __launch_bounds__(256) void k_gemm_qkv(const _Float16* __restrict__ Wqk,
        const _Float16* __restrict__ Wv, const _Float16* __restrict__ XT,
        const float* __restrict__ vbias, _Float16* __restrict__ Vb,
        _Float16* __restrict__ Qg, _Float16* __restrict__ Kt) {
    __shared__ _Float16 EpB[64][72];
    const int b = blockIdx.z, y = blockIdx.y, n0 = blockIdx.x * 64;
    const int isV = (y >= 4);
    const int o0 = (isV ? (y - 4) : y) * 64;
    const _Float16* Wb = isV ? Wv : Wqk;
    const int tid = threadIdx.x, w = tid >> 6, quad = (tid >> 4) & 3, tx = tid & 15;
    const _Float16* Arow = Wb + (o0 + w * 16 + tx) * Cch + quad * 8;
    const _Float16* Brow = XT + ((size_t)(b * Npt + n0 + tx) * Cch) + quad * 8;
    f32x4 acc[4];
    #pragma unroll
    for (int s = 0; s < 4; ++s) acc[s] = (f32x4){0.f, 0.f, 0.f, 0.f};
    for (int k0 = 0; k0 < Cch; k0 += 32) {
        f16x8 a = *(const f16x8*)(Arow + k0);
        #pragma unroll
        for (int s = 0; s < 4; ++s) {
            f16x8 bb = *(const f16x8*)(Brow + s * 16 * Cch + k0);
            acc[s] = __builtin_amdgcn_mfma_f32_16x16x32_f16(a, bb, acc[s], 0, 0, 0);
        }
    }
    if (!isV) {
        const int cch = (w << 1) + (quad >> 1);
        const int hof = (quad & 1) * 4;
        #pragma unroll
        for (int s = 0; s < 4; ++s) {
            int ng = n0 + s * 16 + tx;
            f16x4 pk;
            pk[0] = (_Float16)acc[s][0]; pk[1] = (_Float16)acc[s][1];
            pk[2] = (_Float16)acc[s][2]; pk[3] = (_Float16)acc[s][3];
            int rK = ng & 63, jt = ng >> 6;
            size_t ka = ((size_t)((b * Hh + (o0 >> 6)) * 32 + jt) << 12)
                      + rK * 64 + ((cch ^ (rK & 7)) * 8) + hof;
            *(f16x4*)&Kt[ka] = pk;
            int iQ = ((ng & 511) << 2) + (o0 >> 6);
            int rQ = iQ & 63, it = iQ >> 6;
            size_t qa = ((size_t)((b * Hh + (ng >> 9)) * 32 + it) << 12)
                      + rQ * 64 + ((cch ^ (rQ & 7)) * 8) + hof;
            *(f16x4*)&Qg[qa] = pk;
        }
        return;
    }
    float bv[4];
    {
        int ob = o0 + w * 16 + quad * 4;
        bv[0] = vbias[ob]; bv[1] = vbias[ob + 1]; bv[2] = vbias[ob + 2]; bv[3] = vbias[ob + 3];
    }
    #pragma unroll
    for (int s = 0; s < 4; ++s) {
        int ol = w * 16 + quad * 4, nl = s * 16 + tx;
        EpB[ol + 0][nl] = (_Float16)(acc[s][0] + bv[0]);
        EpB[ol + 1][nl] = (_Float16)(acc[s][1] + bv[1]);
        EpB[ol + 2][nl] = (_Float16)(acc[s][2] + bv[2]);
        EpB[ol + 3][nl] = (_Float16)(acc[s][3] + bv[3]);
    }
    __syncthreads();
    int row = tid >> 2, seg = (tid & 3) * 16;
    _Float16* yp = Vb + ((size_t)(b * Cch + o0 + row) * Npt) + n0 + seg;
    #pragma unroll
    for (int g = 0; g < 4; ++g)
        *(f16x4*)(yp + g * 4) = *(f16x4*)&EpB[row][seg + g * 4];
}

// ---------------- attention pass A: 128 i-rows/block, per-lane online (m2,l) ----------------
__global__ __launch_bounds__(256) void k_attn_A(const _Float16* __restrict__ Qg,
        const _Float16* __restrict__ Kt, float* __restrict__ mP, float* __restrict__ lP) {
    __shared__ _Float16 Ksh[2][4096];
    const int bh = blockIdx.z, jc = blockIdx.y, i0 = blockIdx.x * 128;
    const int tid = threadIdx.x, w = tid >> 6, q = (tid >> 4) & 3, tx = tid & 15;
    const int lane = tid & 63;
    const int sx = tx & 7;
    f16x8 qa[2][2];
    #pragma unroll
    for (int g = 0; g < 2; ++g) {
        const _Float16* Qtile = Qg + ((size_t)(bh * 32 + ((i0 + g * 64) >> 6)) << 12);
        int r = w * 16 + tx;
        qa[g][0] = *(const f16x8*)(Qtile + r * 64 + (q ^ sx) * 8);
        qa[g][1] = *(const f16x8*)(Qtile + r * 64 + ((q + 4) ^ sx) * 8);
    }
    const _Float16* Kbase = Kt + ((size_t)(bh * 32) << 12);
    const int jt0 = jc * 8;
    {
        const _Float16* g = Kbase + ((size_t)jt0 << 12) + (w * 2) * 512 + lane * 8;
        gld16(g,       &Ksh[0][(w * 2 + 0) * 512]);
        gld16(g + 512, &Ksh[0][(w * 2 + 1) * 512]);
    }
    __syncthreads();
    float m2[2][4], l[2][4];
    #pragma unroll
    for (int g = 0; g < 2; ++g)
        #pragma unroll
        for (int r = 0; r < 4; ++r) { m2[g][r] = -1e30f; l[g][r] = 0.f; }
    for (int t = 0; t < 8; ++t) {
        if (t < 7) {
            const _Float16* g = Kbase + ((size_t)(jt0 + t + 1) << 12) + (w * 2) * 512 + lane * 8;
            gld16(g,       &Ksh[(t + 1) & 1][(w * 2 + 0) * 512]);
            gld16(g + 512, &Ksh[(t + 1) & 1][(w * 2 + 1) * 512]);
        }
        const _Float16* kbuf = Ksh[t & 1];
        f32x4 e[2][4];
        #pragma unroll
        for (int s = 0; s < 4; ++s) {
            int r = s * 16 + tx;
            f16x8 kb0 = *(const f16x8*)(kbuf + r * 64 + (q ^ sx) * 8);
            f16x8 kb1 = *(const f16x8*)(kbuf + r * 64 + ((q + 4) ^ sx) * 8);
            #pragma unroll
            for (int g = 0; g < 2; ++g) {
                f32x4 z = (f32x4){0.f, 0.f, 0.f, 0.f};
                z = __builtin_amdgcn_mfma_f32_16x16x32_f16(qa[g][0], kb0, z, 0, 0, 0);
                e[g][s] = __builtin_amdgcn_mfma_f32_16x16x32_f16(qa[g][1], kb1, z, 0, 0, 0);
            }
        }
        #pragma unroll
        for (int g = 0; g < 2; ++g)
            #pragma unroll
            for (int r = 0; r < 4; ++r) {
                float e0 = e[g][0][r] * L2E, e1 = e[g][1][r] * L2E;
                float e2 = e[g][2][r] * L2E, e3 = e[g][3][r] * L2E;
                float lm = fmaxf(fmaxf(e0, e1), fmaxf(e2, e3));
                float nm = fmaxf(m2[g][r], lm);
                l[g][r] = l[g][r] * fexp2(m2[g][r] - nm)
                        + fexp2(e0 - nm) + fexp2(e1 - nm) + fexp2(e2 - nm) + fexp2(e3 - nm);
                m2[g][r] = nm;
            }
        __syncthreads();
    }
    #pragma unroll
    for (int g = 0; g < 2; ++g)
        #pragma unroll
        for (int r = 0; r < 4; ++r) {
            float mm = m2[g][r], ll = l[g][r];
            #pragma unroll
            for (int off = 1; off < 16; off <<= 1) {
                float om = __shfl_xor(mm, off), ol = __shfl_xor(ll, off);
                float nm = fmaxf(mm, om);
                ll = ll * fexp2(mm - nm) + ol * fexp2(om - nm);
                mm = nm;
            }
            if (tx == 0) {
                int idx = bh * Npt + i0 + g * 64 + w * 16 + q * 4 + r;
                mP[jc * NROW + idx] = mm;
                lP[jc * NROW + idx] = ll;
            }
        }
}

// ---------------- combine chunk (m2,l) partials -> rowm2, rowli2 = L2E/l ----------------
__global__ void k_mlcomb(const float* __restrict__ mP, const float* __restrict__ lP,
                         float* __restrict__ rowm2, float* __restrict__ rowli2) {
    int row = blockIdx.x * 256 + threadIdx.x;    // NROW threads
    float m0 = mP[row], m1 = mP[NROW + row], m2 = mP[2 * NROW + row], m3 = mP[3 * NROW + row];
    float m = fmaxf(fmaxf(m0, m1), fmaxf(m2, m3));
    float l = lP[row] * fexp2(m0 - m) + lP[NROW + row] * fexp2(m1 - m)
            + lP[2 * NROW + row] * fexp2(m2 - m) + lP[3 * NROW + row] * fexp2(m3 - m);
    rowm2[row] = m;
    rowli2[row] = L2E / l;
}

// ---------------- attention pass B: 32-col j-tiles, wave-private 512-row i-chunks ----------------
// grid (64 j-tiles, 16 bh) = 1024 blocks (4 blocks/CU). Wave w owns i-chunk w (512 rows)
// x 32 j-cols. Halved per-wave state (kb[2], Tacc[4][2], 4KB AtT) keeps VGPR under the
// 4-waves/SIMD budget; trip count stays 8 so the loop stays rolled (round-8/10 lesson:
// small trip counts get unrolled regardless of pragmas and balloon VGPR to 156).
__global__ __launch_bounds__(256) void k_attn_B(const _Float16* __restrict__ Qg,
        const _Float16* __restrict__ Kt, const _Float16* __restrict__ Vb,
        const float* __restrict__ rowm2, const float* __restrict__ rowli2,
        _Float16* __restrict__ Tp, float* __restrict__ Sp) {
    __shared__ _Float16 AtT[4][2048];     // per-wave 4KB swizzled P scratch (32 j x 64 i)
    const int bh = blockIdx.y, j0 = blockIdx.x * 32;
    const int b = bh >> 2, hd = bh & 3;
    const int tid = threadIdx.x, w = tid >> 6, q = (tid >> 4) & 3, tx = tid & 15;
    const int sx = tx & 7;
    const int jr = j0 & 32;               // row offset inside the 64-row K tile
    f16x8 kb[2][2];
    const _Float16* Ktile = Kt + ((size_t)(bh * 32 + (j0 >> 6)) << 12);
    #pragma unroll
    for (int nt = 0; nt < 2; ++nt) {
        int r = jr + nt * 16 + tx;
        kb[nt][0] = *(const f16x8*)(Ktile + r * 64 + (q ^ sx) * 8);
        kb[nt][1] = *(const f16x8*)(Ktile + r * 64 + ((q + 4) ^ sx) * 8);
    }
    f32x4 Tacc[4][2];
    #pragma unroll
    for (int mt = 0; mt < 4; ++mt)
        #pragma unroll
        for (int nt = 0; nt < 2; ++nt) Tacc[mt][nt] = (f32x4){0.f, 0.f, 0.f, 0.f};
    float scS[2] = {0.f, 0.f};
    _Float16* myAt = AtT[w];
    const _Float16* vbase = Vb + (size_t)(b * Cch + hd * 64) * Npt;
    const float* m2b = rowm2 + bh * Npt;
    const float* lib = rowli2 + bh * Npt;
    for (int it = 0; it < 8; ++it) {
        const int i0 = w * 512 + it * 64;
        const _Float16* Qtile = Qg + ((size_t)(bh * 32 + (i0 >> 6)) << 12);
        #pragma unroll
        for (int mt = 0; mt < 4; ++mt) {
            int r = mt * 16 + tx;
            f16x8 qa0 = *(const f16x8*)(Qtile + r * 64 + (q ^ sx) * 8);
            f16x8 qa1 = *(const f16x8*)(Qtile + r * 64 + ((q + 4) ^ sx) * 8);
            float4 m2v = *(const float4*)(m2b + i0 + mt * 16 + q * 4);
            float4 liv = *(const float4*)(lib + i0 + mt * 16 + q * 4);
            #pragma unroll
            for (int nt = 0; nt < 2; ++nt) {
                f32x4 z = (f32x4){0.f, 0.f, 0.f, 0.f};
                z = __builtin_amdgcn_mfma_f32_16x16x32_f16(qa0, kb[nt][0], z, 0, 0, 0);
                z = __builtin_amdgcn_mfma_f32_16x16x32_f16(qa1, kb[nt][1], z, 0, 0, 0);
                float a0 = fexp2(fexp2(__builtin_fmaf(z[0], L2E, -m2v.x)) * liv.x);
                float a1 = fexp2(fexp2(__builtin_fmaf(z[1], L2E, -m2v.y)) * liv.y);
                float a2 = fexp2(fexp2(__builtin_fmaf(z[2], L2E, -m2v.z)) * liv.z);
                float a3 = fexp2(fexp2(__builtin_fmaf(z[3], L2E, -m2v.w)) * liv.w);
                scS[nt] += a0 + a1 + a2 + a3;
                f16x4 pk;
                pk[0] = (_Float16)a0; pk[1] = (_Float16)a1;
                pk[2] = (_Float16)a2; pk[3] = (_Float16)a3;
                *(f16x4*)&myAt[(nt * 16 + tx) * 64 + ((2 * mt + (q >> 1)) ^ sx) * 8 + (q & 1) * 4] = pk;
            }
        }
        f16x8 pb[2][2], va[4][2];
        #pragma unroll
        for (int nt = 0; nt < 2; ++nt) {
            int r = nt * 16 + tx;
            pb[nt][0] = *(const f16x8*)&myAt[r * 64 + (q ^ sx) * 8];
            pb[nt][1] = *(const f16x8*)&myAt[r * 64 + ((q + 4) ^ sx) * 8];
        }
        #pragma unroll
        for (int mt = 0; mt < 4; ++mt) {
            const _Float16* vp = vbase + (size_t)(mt * 16 + tx) * Npt + i0 + q * 8;
            va[mt][0] = *(const f16x8*)(vp);
            va[mt][1] = *(const f16x8*)(vp + 32);
        }
        #pragma unroll
        for (int mt = 0; mt < 4; ++mt)
            #pragma unroll
            for (int nt = 0; nt < 2; ++nt) {
                Tacc[mt][nt] = __builtin_amdgcn_mfma_f32_16x16x32_f16(va[mt][0], pb[nt][0], Tacc[mt][nt], 0, 0, 0);
                Tacc[mt][nt] = __builtin_amdgcn_mfma_f32_16x16x32_f16(va[mt][1], pb[nt][1], Tacc[mt][nt], 0, 0, 0);
            }
    }
    const size_t NE = (size_t)Bsz * Cch * Npt;
    #pragma unroll
    for (int mt = 0; mt < 4; ++mt)
        #pragma unroll
        for (int nt = 0; nt < 2; ++nt) {
            int d = hd * 64 + mt * 16 + q * 4;
            int jg = j0 + nt * 16 + tx;
            _Float16* tp = Tp + (size_t)w * NE + (size_t)(b * Cch + d) * Npt + jg;
            tp[0 * Npt] = (_Float16)Tacc[mt][nt][0];
            tp[1 * Npt] = (_Float16)Tacc[mt][nt][1];
            tp[2 * Npt] = (_Float16)Tacc[mt][nt][2];
            tp[3 * Npt] = (_Float16)Tacc[mt][nt][3];
        }
    #pragma unroll
    for (int nt = 0; nt < 2; ++nt) {
        float s = scS[nt];
        s += __shfl_xor(s, 16);
        s += __shfl_xor(s, 32);
        if (q == 0) Sp[(size_t)w * NROW + bh * Npt + j0 + nt * 16 + tx] = s;
    }
}

// ---------------- reduce T/S partials (4), u = h - T/S, transpose+cast -> XT ----------------
__global__ __launch_bounds__(256) void k_redT_fuse(const float* __restrict__ h,
        const _Float16* __restrict__ Tp, const float* __restrict__ Sp,
        _Float16* __restrict__ XT) {
    __shared__ _Float16 Tt[64][72];
    __shared__ float rsL[64];
    const int b = blockIdx.z, c0 = blockIdx.y * 64, n0 = blockIdx.x * 64;
    const int t = threadIdx.x;
    const int bh = b * Hh + (c0 >> 6);
    if (t < 64) {
        float s = 0.f;
        #pragma unroll
        for (int ic = 0; ic < NIC; ++ic) s += Sp[(size_t)ic * NROW + bh * Npt + n0 + t];
        rsL[t] = 1.f / s;
    }
    __syncthreads();
    const int cl = t >> 2, ns = (t & 3) * 16;
    const size_t NE = (size_t)Bsz * Cch * Npt;
    const size_t rowoff = ((size_t)(b * Cch + c0 + cl) * Npt) + n0 + ns;
    float tv[16];
    #pragma unroll
    for (int e = 0; e < 16; ++e) tv[e] = 0.f;
    #pragma unroll
    for (int ic = 0; ic < NIC; ++ic) {
        const _Float16* qq = Tp + (size_t)ic * NE + rowoff;
        #pragma unroll
        for (int g = 0; g < 2; ++g) {
            f16x8 vv = *(const f16x8*)(qq + g * 8);
            #pragma unroll
            for (int e = 0; e < 8; ++e) tv[g * 8 + e] += (float)vv[e];
        }
    }
    const float* hp = h + rowoff;
    #pragma unroll
    for (int g = 0; g < 4; ++g) {
        float4 hv = *(const float4*)(hp + g * 4);
        Tt[ns + g * 4 + 0][cl] = (_Float16)(hv.x - tv[g * 4 + 0] * rsL[ns + g * 4 + 0]);
        Tt[ns + g * 4 + 1][cl] = (_Float16)(hv.y - tv[g * 4 + 1] * rsL[ns + g * 4 + 1]);
        Tt[ns + g * 4 + 2][cl] = (_Float16)(hv.z - tv[g * 4 + 2] * rsL[ns + g * 4 + 2]);
        Tt[ns + g * 4 + 3][cl] = (_Float16)(hv.w - tv[g * 4 + 3] * rsL[ns + g * 4 + 3]);
    }
    __syncthreads();
    int nl = t >> 2, cs = (t & 3) * 16;
    _Float16* op = XT + ((size_t)(b * Npt + n0 + nl) * Cch) + c0 + cs;
    #pragma unroll
    for (int g = 0; g < 4; ++g)
        *(f16x4*)(op + g * 4) = *(f16x4*)&Tt[nl][cs + g * 4];
}

// ---- fused BN(from atomically-accumulated stats) + relu + residual + out + transpose -> XT ----
__global__ __launch_bounds__(256) void k_bn_fuse(const float* __restrict__ t,
        const float* __restrict__ bnacc,
        const float* __restrict__ g, const float* __restrict__ bt,
        const float* __restrict__ emb, const float* __restrict__ resid,
        float* __restrict__ hout, float* __restrict__ out, _Float16* __restrict__ XT,
        int layer) {
    __shared__ _Float16 Tt[64][72];
    const int b = blockIdx.z, c0 = blockIdx.y * 64, n0 = blockIdx.x * 64;
    const int tt = threadIdx.x;
    const int cl = tt >> 2, ns = (tt & 3) * 16;
    const int c = c0 + cl;
    const float mn = bnacc[c] * (1.f / BN_CNT);
    const float var = bnacc[256 + c] * (1.f / BN_CNT) - mn * mn;
    const float is = rsqrtf(var + EPSV);
    const float gg = g[c], bb = bt[c];
    const size_t rowoff = ((size_t)(b * Cch + c) * Npt) + n0 + ns;
    const float* tp = t + rowoff;
    const float* ep = emb + rowoff;
    const float* rp = resid ? resid + rowoff : nullptr;
    float* hp = hout + rowoff;
    float* op = out ? out + (size_t)b * (NL * Cch * Npt) + (size_t)(layer * Cch + c) * Npt + n0 + ns
                    : nullptr;
    #pragma unroll
    for (int gi = 0; gi < 4; ++gi) {
        float4 v = *(const float4*)(tp + gi * 4);
        float4 y;
        y.x = fmaxf(gg * (v.x - mn) * is + bb, 0.f);
        y.y = fmaxf(gg * (v.y - mn) * is + bb, 0.f);
        y.z = fmaxf(gg * (v.z - mn) * is + bb, 0.f);
        y.w = fmaxf(gg * (v.w - mn) * is + bb, 0.f);
        if (rp) {
            float4 r = *(const float4*)(rp + gi * 4);
            y.x += r.x; y.y += r.y; y.z += r.z; y.w += r.w;
        }
        *(float4*)(hp + gi * 4) = y;
        if (op) *(float4*)(op + gi * 4) = y;
        float4 e = *(const float4*)(ep + gi * 4);
        Tt[ns + gi * 4 + 0][cl] = (_Float16)(y.x + e.x);
        Tt[ns + gi * 4 + 1][cl] = (_Float16)(y.y + e.y);
        Tt[ns + gi * 4 + 2][cl] = (_Float16)(y.z + e.z);
        Tt[ns + gi * 4 + 3][cl] = (_Float16)(y.w + e.w);
    }
    __syncthreads();
    int nl = tt >> 2, cs = (tt & 3) * 16;
    _Float16* xp = XT + ((size_t)(b * Npt + n0 + nl) * Cch) + c0 + cs;
    #pragma unroll
    for (int gi = 0; gi < 4; ++gi)
        *(f16x4*)(xp + gi * 4) = *(f16x4*)&Tt[nl][cs + gi * 4];
}

extern "C" void kernel_launch(void* const* d_in, const int* in_sizes, int n_in,
                              void* d_out, int out_size, void* d_ws, size_t ws_size,
                              hipStream_t stream) {
    (void)in_sizes; (void)n_in; (void)out_size; (void)ws_size;
    const float* x    = (const float*)d_in[0];
    const float* xyz  = (const float*)d_in[1];
    const float* c1w  = (const float*)d_in[2];
    const float* posw = (const float*)d_in[3];
    const float* posb = (const float*)d_in[4];
    const float* bn1g = (const float*)d_in[5];
    const float* bn1b = (const float*)d_in[6];
    const float* qkw  = (const float*)d_in[7];
    const float* vw   = (const float*)d_in[8];
    const float* vb   = (const float*)d_in[9];
    const float* tw   = (const float*)d_in[10];
    const float* tb   = (const float*)d_in[11];
    const float* bng  = (const float*)d_in[12];
    const float* bnb  = (const float*)d_in[13];
    float* out = (float*)d_out;

    const size_t NE = (size_t)Bsz * Cch * Npt;   // 2,097,152
    char* W = (char*)d_ws;
    float* emb   = (float*)W;                 W += NE * 4;
    float* h     = (float*)W;                 W += NE * 4;
    float* vbuf  = (float*)W;                 W += NE * 4;   // fp32 conv outputs
    _Float16* Tp = (_Float16*)W;              W += (size_t)NIC * NE * 2;   // 4 fp16 partials
    _Float16* XT = (_Float16*)W;              W += NE * 2;
    _Float16* Qg = (_Float16*)W;              W += NE * 2;
    _Float16* Kt = (_Float16*)W;              W += NE * 2;
    _Float16* Vb = (_Float16*)W;              W += NE * 2;
    _Float16* wbf = (_Float16*)W;             W += 851968 * 2;
    float* rowm2 = (float*)W;                 W += NROW * 4;
    float* rowli2 = (float*)W;                W += NROW * 4;
    float* mP    = (float*)W;                 W += 4 * NROW * 4;
    float* lP    = (float*)W;                 W += 4 * NROW * 4;
    float* Sp    = (float*)W;                 W += NIC * NROW * 4;
    float* bnacc = (float*)W;                 W += 5 * 512 * 4;   // 5 slots x (sum,sum2)

    dim3 blk(256);
    dim3 g4(Npt / 64, Cch / 64, Bsz);    // 32,4,4
    dim3 gQKV(Npt / 64, 8, Bsz);         // 32,8,4 — fused qk+v
    dim3 gA(Npt / 128, 4, 16);           // attention pass A (128 i-rows/block)
    dim3 gB(Npt / 32, 16);               // attention pass B (64 j-tiles x 16 bh = 1024 blocks)
    int ew = (int)(NE / 256);

    k_castw<<<3328, blk, 0, stream>>>(c1w, qkw, vw, tw, wbf, bnacc);
    k_xyz_emb<<<ew, blk, 0, stream>>>(xyz, posw, posb, emb);

    // h0 = relu(bn1(conv1_w @ x)); XT = transpose(h0 + emb)
    k_fuse_t<<<g4, blk, 0, stream>>>(x, XT);
    k_gemm_mfma<<<g4, blk, 0, stream>>>(wbf, XT, nullptr, vbuf, bnacc);
    k_bn_fuse<<<g4, blk, 0, stream>>>(vbuf, bnacc, bn1g, bn1b, emb, nullptr,
                                      h, nullptr, XT, 0);

    for (int L = 0; L < NL; ++L) {
        const _Float16* qkL = wbf + 65536 + (size_t)L * 65536;
        const _Float16* vL  = wbf + 327680 + (size_t)L * 65536;
        const _Float16* tL  = wbf + 589824 + (size_t)L * 65536;
        float* accL = bnacc + (1 + L) * 512;
        k_gemm_qkv<<<gQKV, blk, 0, stream>>>(qkL, vL, XT, vb + L * Cch, Vb, Qg, Kt);
        k_attn_A<<<gA, blk, 0, stream>>>(Qg, Kt, mP, lP);
        k_mlcomb<<<NROW / 256, blk, 0, stream>>>(mP, lP, rowm2, rowli2);
        k_attn_B<<<gB, blk, 0, stream>>>(Qg, Kt, Vb, rowm2, rowli2, Tp, Sp);
        k_redT_fuse<<<g4, blk, 0, stream>>>(h, Tp, Sp, XT);
        k_gemm_mfma<<<g4, blk, 0, stream>>>(tL, XT, tb + L * Cch, vbuf, accL);
        k_bn_fuse<<<g4, blk, 0, stream>>>(vbuf, accL, bng + L * Cch, bnb + L * Cch,
                                          emb, h, h, out, XT, L);
    }
}

// Round 12
// 641.251 us; speedup vs baseline: 1.1303x; 1.0475x over previous
//
#include <hip/hip_runtime.h>
#include <math.h>

#define Bsz 4
#define Cch 256
#define Npt 2048
#define Hh  4
#define NL  4
#define BN_CNT (Bsz * Npt)   // 8192
#define EPSV 1e-5f
#define NROW (16 * Npt)      // 32768 attention rows total (bh * Npt)
#define L2E 1.44269504f
#define NIC 4                // i-chunk partials in attention pass B (== waves/block)

typedef _Float16 f16x8 __attribute__((ext_vector_type(8)));
typedef _Float16 f16x4 __attribute__((ext_vector_type(4)));
typedef float    f32x4 __attribute__((ext_vector_type(4)));

__device__ __forceinline__ float fexp2(float x) { return __builtin_amdgcn_exp2f(x); }

// ---------------- xyz embedding ----------------
__global__ void k_xyz_emb(const float* __restrict__ xyz, const float* __restrict__ pw,
                          const float* __restrict__ pb, float* __restrict__ emb) {
    int idx = blockIdx.x * 256 + threadIdx.x;
    int n = idx & (Npt - 1);
    int c = (idx >> 11) & (Cch - 1);
    int b = idx >> 19;
    const float* xz = xyz + (b * Npt + n) * 3;
    emb[idx] = pw[c * 3 + 0] * xz[0] + pw[c * 3 + 1] * xz[1] + pw[c * 3 + 2] * xz[2] + pb[c];
}

// ---------------- cast all weights to fp16; zero BN accumulators ----------------
__global__ void k_castw(const float* __restrict__ c1w, const float* __restrict__ qkw,
                        const float* __restrict__ vw, const float* __restrict__ tw,
                        _Float16* __restrict__ o, float* __restrict__ bnacc) {
    int i = blockIdx.x * 256 + threadIdx.x;
    if (i < 5 * 512) bnacc[i] = 0.f;     // 5 slots x (sum[256], sum2[256])
    const float* src; int off;
    if (i < 65536)            { src = c1w; off = i; }
    else if (i < 327680)      { src = qkw; off = i - 65536; }
    else if (i < 589824)      { src = vw;  off = i - 327680; }
    else                      { src = tw;  off = i - 589824; }
    o[i] = (_Float16)src[off];
}

// ---------------- transpose + cast x -> XT[b][n][c] (entry only) ----------------
__global__ __launch_bounds__(256) void k_fuse_t(const float* __restrict__ in,
        _Float16* __restrict__ XT) {
    __shared__ _Float16 Tt[64][72];
    const int b = blockIdx.z, c0 = blockIdx.y * 64, n0 = blockIdx.x * 64;
    const int t = threadIdx.x;
    const int cl = t >> 2, ns = (t & 3) * 16;
    const float* ip = in + ((size_t)(b * Cch + c0 + cl) * Npt) + n0 + ns;
    #pragma unroll
    for (int g = 0; g < 4; ++g) {
        float4 v = *(const float4*)(ip + g * 4);
        Tt[ns + g * 4 + 0][cl] = (_Float16)v.x;
        Tt[ns + g * 4 + 1][cl] = (_Float16)v.y;
        Tt[ns + g * 4 + 2][cl] = (_Float16)v.z;
        Tt[ns + g * 4 + 3][cl] = (_Float16)v.w;
    }
    __syncthreads();
    int nl = t >> 2, cs = (t & 3) * 16;
    _Float16* op = XT + ((size_t)(b * Npt + n0 + nl) * Cch) + c0 + cs;
    #pragma unroll
    for (int g = 0; g < 4; ++g)
        *(f16x4*)(op + g * 4) = *(f16x4*)&Tt[nl][cs + g * 4];
}

// ---------------- MFMA GEMM (fp32 out) + fused BN partial-stat atomics ----------------
__global__ __launch_bounds__(256) void k_gemm_mfma(const _Float16* __restrict__ Wb,
        const _Float16* __restrict__ XT, const float* __restrict__ bias,
        float* __restrict__ Yf, float* __restrict__ bnacc) {
    __shared__ float EpF[64][68];
    const int b = blockIdx.z, o0 = blockIdx.y * 64, n0 = blockIdx.x * 64;
    const int tid = threadIdx.x, w = tid >> 6, quad = (tid >> 4) & 3, tx = tid & 15;
    const _Float16* Arow = Wb + (o0 + w * 16 + tx) * Cch + quad * 8;
    const _Float16* Brow = XT + ((size_t)(b * Npt + n0 + tx) * Cch) + quad * 8;
    f32x4 acc[4];
    #pragma unroll
    for (int s = 0; s < 4; ++s) acc[s] = (f32x4){0.f, 0.f, 0.f, 0.f};
    for (int k0 = 0; k0 < Cch; k0 += 32) {
        f16x8 a = *(const f16x8*)(Arow + k0);
        #pragma unroll
        for (int s = 0; s < 4; ++s) {
            f16x8 bb = *(const f16x8*)(Brow + s * 16 * Cch + k0);
            acc[s] = __builtin_amdgcn_mfma_f32_16x16x32_f16(a, bb, acc[s], 0, 0, 0);
        }
    }
    float bv[4];
    {
        int ob = o0 + w * 16 + quad * 4;
        if (bias) { bv[0] = bias[ob]; bv[1] = bias[ob + 1]; bv[2] = bias[ob + 2]; bv[3] = bias[ob + 3]; }
        else bv[0] = bv[1] = bv[2] = bv[3] = 0.f;
    }
    #pragma unroll
    for (int s = 0; s < 4; ++s) {
        int ol = w * 16 + quad * 4, nl = s * 16 + tx;
        EpF[ol + 0][nl] = acc[s][0] + bv[0];
        EpF[ol + 1][nl] = acc[s][1] + bv[1];
        EpF[ol + 2][nl] = acc[s][2] + bv[2];
        EpF[ol + 3][nl] = acc[s][3] + bv[3];
    }
    __syncthreads();
    int row = tid >> 2, seg = (tid & 3) * 16;
    float* yp = Yf + ((size_t)(b * Cch + o0 + row) * Npt) + n0 + seg;
    float s1 = 0.f, s2 = 0.f;
    #pragma unroll
    for (int g = 0; g < 4; ++g) {
        float4 v = *(float4*)&EpF[row][seg + g * 4];
        *(float4*)(yp + g * 4) = v;
        s1 += v.x + v.y + v.z + v.w;
        s2 += v.x * v.x + v.y * v.y + v.z * v.z + v.w * v.w;
    }
    s1 += __shfl_xor(s1, 1); s2 += __shfl_xor(s2, 1);
    s1 += __shfl_xor(s1, 2); s2 += __shfl_xor(s2, 2);
    if ((tid & 3) == 0) {
        atomicAdd(&bnacc[o0 + row], s1);
        atomicAdd(&bnacc[256 + o0 + row], s2);
    }
}

// ---------------- fused qk + v GEMM: y<4 -> Qg/Kt (swizzled), y>=4 -> Vb fp16 ----------------
__global__ __launch_bounds__(256) void k_gemm_qkv(const _Float16* __restrict__ Wqk,
        const _Float16* __restrict__ Wv, const _Float16* __restrict__ XT,
        const float* __restrict__ vbias, _Float16* __restrict__ Vb,
        _Float16* __restrict__ Qg, _Float16* __restrict__ Kt) {
    __shared__ _Float16 EpB[64][72];
    const int b = blockIdx.z, y = blockIdx.y, n0 = blockIdx.x * 64;
    const int isV = (y >= 4);
    const int o0 = (isV ? (y - 4) : y) * 64;
    const _Float16* Wb = isV ? Wv : Wqk;
    const int tid = threadIdx.x, w = tid >> 6, quad = (tid >> 4) & 3, tx = tid & 15;
    const _Float16* Arow = Wb + (o0 + w * 16 + tx) * Cch + quad * 8;
    const _Float16* Brow = XT + ((size_t)(b * Npt + n0 + tx) * Cch) + quad * 8;
    f32x4 acc[4];
    #pragma unroll
    for (int s = 0; s < 4; ++s) acc[s] = (f32x4){0.f, 0.f, 0.f, 0.f};
    for (int k0 = 0; k0 < Cch; k0 += 32) {
        f16x8 a = *(const f16x8*)(Arow + k0);
        #pragma unroll
        for (int s = 0; s < 4; ++s) {
            f16x8 bb = *(const f16x8*)(Brow + s * 16 * Cch + k0);
            acc[s] = __builtin_amdgcn_mfma_f32_16x16x32_f16(a, bb, acc[s], 0, 0, 0);
        }
    }
    if (!isV) {
        const int cch = (w << 1) + (quad >> 1);
        const int hof = (quad & 1) * 4;
        #pragma unroll
        for (int s = 0; s < 4; ++s) {
            int ng = n0 + s * 16 + tx;
            f16x4 pk;
            pk[0] = (_Float16)acc[s][0]; pk[1] = (_Float16)acc[s][1];
            pk[2] = (_Float16)acc[s][2]; pk[3] = (_Float16)acc[s][3];
            int rK = ng & 63, jt = ng >> 6;
            size_t ka = ((size_t)((b * Hh + (o0 >> 6)) * 32 + jt) << 12)
                      + rK * 64 + ((cch ^ (rK & 7)) * 8) + hof;
            *(f16x4*)&Kt[ka] = pk;
            int iQ = ((ng & 511) << 2) + (o0 >> 6);
            int rQ = iQ & 63, it = iQ >> 6;
            size_t qa = ((size_t)((b * Hh + (ng >> 9)) * 32 + it) << 12)
                      + rQ * 64 + ((cch ^ (rQ & 7)) * 8) + hof;
            *(f16x4*)&Qg[qa] = pk;
        }
        return;
    }
    float bv[4];
    {
        int ob = o0 + w * 16 + quad * 4;
        bv[0] = vbias[ob]; bv[1] = vbias[ob + 1]; bv[2] = vbias[ob + 2]; bv[3] = vbias[ob + 3];
    }
    #pragma unroll
    for (int s = 0; s < 4; ++s) {
        int ol = w * 16 + quad * 4, nl = s * 16 + tx;
        EpB[ol + 0][nl] = (_Float16)(acc[s][0] + bv[0]);
        EpB[ol + 1][nl] = (_Float16)(acc[s][1] + bv[1]);
        EpB[ol + 2][nl] = (_Float16)(acc[s][2] + bv[2]);
        EpB[ol + 3][nl] = (_Float16)(acc[s][3] + bv[3]);
    }
    __syncthreads();
    int row = tid >> 2, seg = (tid & 3) * 16;
    _Float16* yp = Vb + ((size_t)(b * Cch + o0 + row) * Npt) + n0 + seg;
    #pragma unroll
    for (int g = 0; g < 4; ++g)
        *(f16x4*)(yp + g * 4) = *(f16x4*)&EpB[row][seg + g * 4];
}

// ---------------- attention pass A: wave-private j-chunks, ZERO barriers / LDS ----------------
// grid (32 i-tiles, 16 bh), block 256. Wave w owns j in [w*512, (w+1)*512): K frags are
// wave-distinct (no intra-block L2 redundancy — R3's direct-read failure mode). Q loaded
// once per wave. Per-lane online (m2,l) with 4-col batched rescale; butterfly at end.
__global__ __launch_bounds__(256) void k_attn_A(const _Float16* __restrict__ Qg,
        const _Float16* __restrict__ Kt, float* __restrict__ mP, float* __restrict__ lP) {
    const int bh = blockIdx.y, i0 = blockIdx.x * 64;
    const int tid = threadIdx.x, w = tid >> 6, q = (tid >> 4) & 3, tx = tid & 15;
    const int sx = tx & 7;
    f16x8 qa[4][2];
    const _Float16* Qtile = Qg + ((size_t)(bh * 32 + (i0 >> 6)) << 12);
    #pragma unroll
    for (int mt = 0; mt < 4; ++mt) {
        int r = mt * 16 + tx;
        qa[mt][0] = *(const f16x8*)(Qtile + r * 64 + (q ^ sx) * 8);
        qa[mt][1] = *(const f16x8*)(Qtile + r * 64 + ((q + 4) ^ sx) * 8);
    }
    float m2[4][4], l[4][4];
    #pragma unroll
    for (int mt = 0; mt < 4; ++mt)
        #pragma unroll
        for (int r = 0; r < 4; ++r) { m2[mt][r] = -1e30f; l[mt][r] = 0.f; }
    const _Float16* Kbase = Kt + ((size_t)(bh * 32 + w * 8) << 12);
    for (int jt = 0; jt < 8; ++jt) {
        const _Float16* Ktile = Kbase + ((size_t)jt << 12);
        f16x8 kb[4][2];
        #pragma unroll
        for (int nt = 0; nt < 4; ++nt) {
            int r = nt * 16 + tx;
            kb[nt][0] = *(const f16x8*)(Ktile + r * 64 + (q ^ sx) * 8);
            kb[nt][1] = *(const f16x8*)(Ktile + r * 64 + ((q + 4) ^ sx) * 8);
        }
        #pragma unroll
        for (int mt = 0; mt < 4; ++mt) {
            f32x4 e[4];
            #pragma unroll
            for (int nt = 0; nt < 4; ++nt) {
                f32x4 z = (f32x4){0.f, 0.f, 0.f, 0.f};
                z = __builtin_amdgcn_mfma_f32_16x16x32_f16(qa[mt][0], kb[nt][0], z, 0, 0, 0);
                e[nt] = __builtin_amdgcn_mfma_f32_16x16x32_f16(qa[mt][1], kb[nt][1], z, 0, 0, 0);
            }
            #pragma unroll
            for (int r = 0; r < 4; ++r) {
                float e0 = e[0][r] * L2E, e1 = e[1][r] * L2E;
                float e2 = e[2][r] * L2E, e3 = e[3][r] * L2E;
                float lm = fmaxf(fmaxf(e0, e1), fmaxf(e2, e3));
                float nm = fmaxf(m2[mt][r], lm);
                l[mt][r] = l[mt][r] * fexp2(m2[mt][r] - nm)
                         + fexp2(e0 - nm) + fexp2(e1 - nm) + fexp2(e2 - nm) + fexp2(e3 - nm);
                m2[mt][r] = nm;
            }
        }
    }
    #pragma unroll
    for (int mt = 0; mt < 4; ++mt)
        #pragma unroll
        for (int r = 0; r < 4; ++r) {
            float mm = m2[mt][r], ll = l[mt][r];
            #pragma unroll
            for (int off = 1; off < 16; off <<= 1) {
                float om = __shfl_xor(mm, off), ol = __shfl_xor(ll, off);
                float nm = fmaxf(mm, om);
                ll = ll * fexp2(mm - nm) + ol * fexp2(om - nm);
                mm = nm;
            }
            if (tx == 0) {
                int idx = bh * Npt + i0 + mt * 16 + q * 4 + r;
                mP[(size_t)w * NROW + idx] = mm;
                lP[(size_t)w * NROW + idx] = ll;
            }
        }
}

// ---------------- combine chunk (m2,l) partials -> rowm2, rowli2 = L2E/l ----------------
__global__ void k_mlcomb(const float* __restrict__ mP, const float* __restrict__ lP,
                         float* __restrict__ rowm2, float* __restrict__ rowli2) {
    int row = blockIdx.x * 256 + threadIdx.x;    // NROW threads
    float m0 = mP[row], m1 = mP[NROW + row], m2 = mP[2 * NROW + row], m3 = mP[3 * NROW + row];
    float m = fmaxf(fmaxf(m0, m1), fmaxf(m2, m3));
    float l = lP[row] * fexp2(m0 - m) + lP[NROW + row] * fexp2(m1 - m)
            + lP[2 * NROW + row] * fexp2(m2 - m) + lP[3 * NROW + row] * fexp2(m3 - m);
    rowm2[row] = m;
    rowli2[row] = L2E / l;
}

// ---------------- attention pass B: wave-private 512-row i-chunks, ZERO barriers ----------------
// grid (32 j-tiles, 16 bh), block 256. Wave w owns i-chunk w (512 rows) x all 64 j.
// (R7/R9 config — best measured 45.4 µs; occupancy knobs exhausted R6-R11.)
__global__ __launch_bounds__(256) void k_attn_B(const _Float16* __restrict__ Qg,
        const _Float16* __restrict__ Kt, const _Float16* __restrict__ Vb,
        const float* __restrict__ rowm2, const float* __restrict__ rowli2,
        _Float16* __restrict__ Tp, float* __restrict__ Sp) {
    __shared__ _Float16 AtT[4][4096];     // per-wave 8KB swizzled P scratch
    const int bh = blockIdx.y, j0 = blockIdx.x * 64;
    const int b = bh >> 2, hd = bh & 3;
    const int tid = threadIdx.x, w = tid >> 6, q = (tid >> 4) & 3, tx = tid & 15;
    const int sx = tx & 7;
    f16x8 kb[4][2];
    const _Float16* Ktile = Kt + ((size_t)(bh * 32 + (j0 >> 6)) << 12);
    #pragma unroll
    for (int nt = 0; nt < 4; ++nt) {
        int r = nt * 16 + tx;
        kb[nt][0] = *(const f16x8*)(Ktile + r * 64 + (q ^ sx) * 8);
        kb[nt][1] = *(const f16x8*)(Ktile + r * 64 + ((q + 4) ^ sx) * 8);
    }
    f32x4 Tacc[4][4];
    #pragma unroll
    for (int mt = 0; mt < 4; ++mt)
        #pragma unroll
        for (int nt = 0; nt < 4; ++nt) Tacc[mt][nt] = (f32x4){0.f, 0.f, 0.f, 0.f};
    float scS[4] = {0.f, 0.f, 0.f, 0.f};
    _Float16* myAt = AtT[w];
    const _Float16* vbase = Vb + (size_t)(b * Cch + hd * 64) * Npt;
    const float* m2b = rowm2 + bh * Npt;
    const float* lib = rowli2 + bh * Npt;
    for (int it = 0; it < 8; ++it) {
        const int i0 = w * 512 + it * 64;
        const _Float16* Qtile = Qg + ((size_t)(bh * 32 + (i0 >> 6)) << 12);
        #pragma unroll
        for (int mt = 0; mt < 4; ++mt) {
            int r = mt * 16 + tx;
            f16x8 qa0 = *(const f16x8*)(Qtile + r * 64 + (q ^ sx) * 8);
            f16x8 qa1 = *(const f16x8*)(Qtile + r * 64 + ((q + 4) ^ sx) * 8);
            float4 m2v = *(const float4*)(m2b + i0 + mt * 16 + q * 4);
            float4 liv = *(const float4*)(lib + i0 + mt * 16 + q * 4);
            #pragma unroll
            for (int nt = 0; nt < 4; ++nt) {
                f32x4 z = (f32x4){0.f, 0.f, 0.f, 0.f};
                z = __builtin_amdgcn_mfma_f32_16x16x32_f16(qa0, kb[nt][0], z, 0, 0, 0);
                z = __builtin_amdgcn_mfma_f32_16x16x32_f16(qa1, kb[nt][1], z, 0, 0, 0);
                float a0 = fexp2(fexp2(__builtin_fmaf(z[0], L2E, -m2v.x)) * liv.x);
                float a1 = fexp2(fexp2(__builtin_fmaf(z[1], L2E, -m2v.y)) * liv.y);
                float a2 = fexp2(fexp2(__builtin_fmaf(z[2], L2E, -m2v.z)) * liv.z);
                float a3 = fexp2(fexp2(__builtin_fmaf(z[3], L2E, -m2v.w)) * liv.w);
                scS[nt] += a0 + a1 + a2 + a3;
                f16x4 pk;
                pk[0] = (_Float16)a0; pk[1] = (_Float16)a1;
                pk[2] = (_Float16)a2; pk[3] = (_Float16)a3;
                *(f16x4*)&myAt[(nt * 16 + tx) * 64 + ((2 * mt + (q >> 1)) ^ sx) * 8 + (q & 1) * 4] = pk;
            }
        }
        f16x8 pb[4][2], va[4][2];
        #pragma unroll
        for (int nt = 0; nt < 4; ++nt) {
            int r = nt * 16 + tx;
            pb[nt][0] = *(const f16x8*)&myAt[r * 64 + (q ^ sx) * 8];
            pb[nt][1] = *(const f16x8*)&myAt[r * 64 + ((q + 4) ^ sx) * 8];
        }
        #pragma unroll
        for (int mt = 0; mt < 4; ++mt) {
            const _Float16* vp = vbase + (size_t)(mt * 16 + tx) * Npt + i0 + q * 8;
            va[mt][0] = *(const f16x8*)(vp);
            va[mt][1] = *(const f16x8*)(vp + 32);
        }
        #pragma unroll
        for (int mt = 0; mt < 4; ++mt)
            #pragma unroll
            for (int nt = 0; nt < 4; ++nt) {
                Tacc[mt][nt] = __builtin_amdgcn_mfma_f32_16x16x32_f16(va[mt][0], pb[nt][0], Tacc[mt][nt], 0, 0, 0);
                Tacc[mt][nt] = __builtin_amdgcn_mfma_f32_16x16x32_f16(va[mt][1], pb[nt][1], Tacc[mt][nt], 0, 0, 0);
            }
    }
    const size_t NE = (size_t)Bsz * Cch * Npt;
    #pragma unroll
    for (int mt = 0; mt < 4; ++mt)
        #pragma unroll
        for (int nt = 0; nt < 4; ++nt) {
            int d = hd * 64 + mt * 16 + q * 4;
            int jg = j0 + nt * 16 + tx;
            _Float16* tp = Tp + (size_t)w * NE + (size_t)(b * Cch + d) * Npt + jg;
            tp[0 * Npt] = (_Float16)Tacc[mt][nt][0];
            tp[1 * Npt] = (_Float16)Tacc[mt][nt][1];
            tp[2 * Npt] = (_Float16)Tacc[mt][nt][2];
            tp[3 * Npt] = (_Float16)Tacc[mt][nt][3];
        }
    #pragma unroll
    for (int nt = 0; nt < 4; ++nt) {
        float s = scS[nt];
        s += __shfl_xor(s, 16);
        s += __shfl_xor(s, 32);
        if (q == 0) Sp[(size_t)w * NROW + bh * Npt + j0 + nt * 16 + tx] = s;
    }
}

// ---------------- reduce T/S partials (4), u = h - T/S, transpose+cast -> XT ----------------
__global__ __launch_bounds__(256) void k_redT_fuse(const float* __restrict__ h,
        const _Float16* __restrict__ Tp, const float* __restrict__ Sp,
        _Float16* __restrict__ XT) {
    __shared__ _Float16 Tt[64][72];
    __shared__ float rsL[64];
    const int b = blockIdx.z, c0 = blockIdx.y * 64, n0 = blockIdx.x * 64;
    const int t = threadIdx.x;
    const int bh = b * Hh + (c0 >> 6);
    if (t < 64) {
        float s = 0.f;
        #pragma unroll
        for (int ic = 0; ic < NIC; ++ic) s += Sp[(size_t)ic * NROW + bh * Npt + n0 + t];
        rsL[t] = 1.f / s;
    }
    __syncthreads();
    const int cl = t >> 2, ns = (t & 3) * 16;
    const size_t NE = (size_t)Bsz * Cch * Npt;
    const size_t rowoff = ((size_t)(b * Cch + c0 + cl) * Npt) + n0 + ns;
    float tv[16];
    #pragma unroll
    for (int e = 0; e < 16; ++e) tv[e] = 0.f;
    #pragma unroll
    for (int ic = 0; ic < NIC; ++ic) {
        const _Float16* qq = Tp + (size_t)ic * NE + rowoff;
        #pragma unroll
        for (int g = 0; g < 2; ++g) {
            f16x8 vv = *(const f16x8*)(qq + g * 8);
            #pragma unroll
            for (int e = 0; e < 8; ++e) tv[g * 8 + e] += (float)vv[e];
        }
    }
    const float* hp = h + rowoff;
    #pragma unroll
    for (int g = 0; g < 4; ++g) {
        float4 hv = *(const float4*)(hp + g * 4);
        Tt[ns + g * 4 + 0][cl] = (_Float16)(hv.x - tv[g * 4 + 0] * rsL[ns + g * 4 + 0]);
        Tt[ns + g * 4 + 1][cl] = (_Float16)(hv.y - tv[g * 4 + 1] * rsL[ns + g * 4 + 1]);
        Tt[ns + g * 4 + 2][cl] = (_Float16)(hv.z - tv[g * 4 + 2] * rsL[ns + g * 4 + 2]);
        Tt[ns + g * 4 + 3][cl] = (_Float16)(hv.w - tv[g * 4 + 3] * rsL[ns + g * 4 + 3]);
    }
    __syncthreads();
    int nl = t >> 2, cs = (t & 3) * 16;
    _Float16* op = XT + ((size_t)(b * Npt + n0 + nl) * Cch) + c0 + cs;
    #pragma unroll
    for (int g = 0; g < 4; ++g)
        *(f16x4*)(op + g * 4) = *(f16x4*)&Tt[nl][cs + g * 4];
}

// ---- fused BN(from atomically-accumulated stats) + relu + residual + out + transpose -> XT ----
__global__ __launch_bounds__(256) void k_bn_fuse(const float* __restrict__ t,
        const float* __restrict__ bnacc,
        const float* __restrict__ g, const float* __restrict__ bt,
        const float* __restrict__ emb, const float* __restrict__ resid,
        float* __restrict__ hout, float* __restrict__ out, _Float16* __restrict__ XT,
        int layer) {
    __shared__ _Float16 Tt[64][72];
    const int b = blockIdx.z, c0 = blockIdx.y * 64, n0 = blockIdx.x * 64;
    const int tt = threadIdx.x;
    const int cl = tt >> 2, ns = (tt & 3) * 16;
    const int c = c0 + cl;
    const float mn = bnacc[c] * (1.f / BN_CNT);
    const float var = bnacc[256 + c] * (1.f / BN_CNT) - mn * mn;
    const float is = rsqrtf(var + EPSV);
    const float gg = g[c], bb = bt[c];
    const size_t rowoff = ((size_t)(b * Cch + c) * Npt) + n0 + ns;
    const float* tp = t + rowoff;
    const float* ep = emb + rowoff;
    const float* rp = resid ? resid + rowoff : nullptr;
    float* hp = hout + rowoff;
    float* op = out ? out + (size_t)b * (NL * Cch * Npt) + (size_t)(layer * Cch + c) * Npt + n0 + ns
                    : nullptr;
    #pragma unroll
    for (int gi = 0; gi < 4; ++gi) {
        float4 v = *(const float4*)(tp + gi * 4);
        float4 y;
        y.x = fmaxf(gg * (v.x - mn) * is + bb, 0.f);
        y.y = fmaxf(gg * (v.y - mn) * is + bb, 0.f);
        y.z = fmaxf(gg * (v.z - mn) * is + bb, 0.f);
        y.w = fmaxf(gg * (v.w - mn) * is + bb, 0.f);
        if (rp) {
            float4 r = *(const float4*)(rp + gi * 4);
            y.x += r.x; y.y += r.y; y.z += r.z; y.w += r.w;
        }
        *(float4*)(hp + gi * 4) = y;
        if (op) *(float4*)(op + gi * 4) = y;
        float4 e = *(const float4*)(ep + gi * 4);
        Tt[ns + gi * 4 + 0][cl] = (_Float16)(y.x + e.x);
        Tt[ns + gi * 4 + 1][cl] = (_Float16)(y.y + e.y);
        Tt[ns + gi * 4 + 2][cl] = (_Float16)(y.z + e.z);
        Tt[ns + gi * 4 + 3][cl] = (_Float16)(y.w + e.w);
    }
    __syncthreads();
    int nl = tt >> 2, cs = (tt & 3) * 16;
    _Float16* xp = XT + ((size_t)(b * Npt + n0 + nl) * Cch) + c0 + cs;
    #pragma unroll
    for (int gi = 0; gi < 4; ++gi)
        *(f16x4*)(xp + gi * 4) = *(f16x4*)&Tt[nl][cs + gi * 4];
}

extern "C" void kernel_launch(void* const* d_in, const int* in_sizes, int n_in,
                              void* d_out, int out_size, void* d_ws, size_t ws_size,
                              hipStream_t stream) {
    (void)in_sizes; (void)n_in; (void)out_size; (void)ws_size;
    const float* x    = (const float*)d_in[0];
    const float* xyz  = (const float*)d_in[1];
    const float* c1w  = (const float*)d_in[2];
    const float* posw = (const float*)d_in[3];
    const float* posb = (const float*)d_in[4];
    const float* bn1g = (const float*)d_in[5];
    const float* bn1b = (const float*)d_in[6];
    const float* qkw  = (const float*)d_in[7];
    const float* vw   = (const float*)d_in[8];
    const float* vb   = (const float*)d_in[9];
    const float* tw   = (const float*)d_in[10];
    const float* tb   = (const float*)d_in[11];
    const float* bng  = (const float*)d_in[12];
    const float* bnb  = (const float*)d_in[13];
    float* out = (float*)d_out;

    const size_t NE = (size_t)Bsz * Cch * Npt;   // 2,097,152
    char* W = (char*)d_ws;
    float* emb   = (float*)W;                 W += NE * 4;
    float* h     = (float*)W;                 W += NE * 4;
    float* vbuf  = (float*)W;                 W += NE * 4;   // fp32 conv outputs
    _Float16* Tp = (_Float16*)W;              W += (size_t)NIC * NE * 2;   // 4 fp16 partials
    _Float16* XT = (_Float16*)W;              W += NE * 2;
    _Float16* Qg = (_Float16*)W;              W += NE * 2;
    _Float16* Kt = (_Float16*)W;              W += NE * 2;
    _Float16* Vb = (_Float16*)W;              W += NE * 2;
    _Float16* wbf = (_Float16*)W;             W += 851968 * 2;
    float* rowm2 = (float*)W;                 W += NROW * 4;
    float* rowli2 = (float*)W;                W += NROW * 4;
    float* mP    = (float*)W;                 W += 4 * NROW * 4;
    float* lP    = (float*)W;                 W += 4 * NROW * 4;
    float* Sp    = (float*)W;                 W += NIC * NROW * 4;
    float* bnacc = (float*)W;                 W += 5 * 512 * 4;   // 5 slots x (sum,sum2)

    dim3 blk(256);
    dim3 g4(Npt / 64, Cch / 64, Bsz);    // 32,4,4
    dim3 gQKV(Npt / 64, 8, Bsz);         // 32,8,4 — fused qk+v
    dim3 gA(Npt / 64, 16);               // attention pass A (wave-private j-chunks)
    dim3 gB(Npt / 64, 16);               // attention pass B (wave-private i-chunks)
    int ew = (int)(NE / 256);

    k_castw<<<3328, blk, 0, stream>>>(c1w, qkw, vw, tw, wbf, bnacc);
    k_xyz_emb<<<ew, blk, 0, stream>>>(xyz, posw, posb, emb);

    // h0 = relu(bn1(conv1_w @ x)); XT = transpose(h0 + emb)
    k_fuse_t<<<g4, blk, 0, stream>>>(x, XT);
    k_gemm_mfma<<<g4, blk, 0, stream>>>(wbf, XT, nullptr, vbuf, bnacc);
    k_bn_fuse<<<g4, blk, 0, stream>>>(vbuf, bnacc, bn1g, bn1b, emb, nullptr,
                                      h, nullptr, XT, 0);

    for (int L = 0; L < NL; ++L) {
        const _Float16* qkL = wbf + 65536 + (size_t)L * 65536;
        const _Float16* vL  = wbf + 327680 + (size_t)L * 65536;
        const _Float16* tL  = wbf + 589824 + (size_t)L * 65536;
        float* accL = bnacc + (1 + L) * 512;
        k_gemm_qkv<<<gQKV, blk, 0, stream>>>(qkL, vL, XT, vb + L * Cch, Vb, Qg, Kt);
        k_attn_A<<<gA, blk, 0, stream>>>(Qg, Kt, mP, lP);
        k_mlcomb<<<NROW / 256, blk, 0, stream>>>(mP, lP, rowm2, rowli2);
        k_attn_B<<<gB, blk, 0, stream>>>(Qg, Kt, Vb, rowm2, rowli2, Tp, Sp);
        k_redT_fuse<<<g4, blk, 0, stream>>>(h, Tp, Sp, XT);
        k_gemm_mfma<<<g4, blk, 0, stream>>>(tL, XT, tb + L * Cch, vbuf, accL);
        k_bn_fuse<<<g4, blk, 0, stream>>>(vbuf, accL, bng + L * Cch, bnb + L * Cch,
                                          emb, h, h, out, XT, L);
    }
}

// Round 13
// 620.591 us; speedup vs baseline: 1.1680x; 1.0333x over previous
//
#include <hip/hip_runtime.h>
#include <math.h>

#define Bsz 4
#define Cch 256
#define Npt 2048
#define Hh  4
#define NL  4
#define BN_CNT (Bsz * Npt)   // 8192
#define EPSV 1e-5f
#define NROW (16 * Npt)      // 32768 attention rows total (bh * Npt)
#define L2E 1.44269504f
#define NIC 4                // i-chunk partials in attention pass B (== waves/block)

typedef _Float16 f16x8 __attribute__((ext_vector_type(8)));
typedef _Float16 f16x4 __attribute__((ext_vector_type(4)));
typedef float    f32x4 __attribute__((ext_vector_type(4)));

__device__ __forceinline__ float fexp2(float x) { return __builtin_amdgcn_exp2f(x); }

// async global->LDS, 16B per lane
__device__ __forceinline__ void gld16(const _Float16* g, _Float16* l) {
    __builtin_amdgcn_global_load_lds(
        (const __attribute__((address_space(1))) unsigned int*)g,
        (__attribute__((address_space(3))) unsigned int*)l, 16, 0, 0);
}

// ---------------- xyz embedding ----------------
__global__ void k_xyz_emb(const float* __restrict__ xyz, const float* __restrict__ pw,
                          const float* __restrict__ pb, float* __restrict__ emb) {
    int idx = blockIdx.x * 256 + threadIdx.x;
    int n = idx & (Npt - 1);
    int c = (idx >> 11) & (Cch - 1);
    int b = idx >> 19;
    const float* xz = xyz + (b * Npt + n) * 3;
    emb[idx] = pw[c * 3 + 0] * xz[0] + pw[c * 3 + 1] * xz[1] + pw[c * 3 + 2] * xz[2] + pb[c];
}

// ---------------- cast all weights to fp16; zero BN accumulators ----------------
__global__ void k_castw(const float* __restrict__ c1w, const float* __restrict__ qkw,
                        const float* __restrict__ vw, const float* __restrict__ tw,
                        _Float16* __restrict__ o, float* __restrict__ bnacc) {
    int i = blockIdx.x * 256 + threadIdx.x;
    if (i < 5 * 512) bnacc[i] = 0.f;     // 5 slots x (sum[256], sum2[256])
    const float* src; int off;
    if (i < 65536)            { src = c1w; off = i; }
    else if (i < 327680)      { src = qkw; off = i - 65536; }
    else if (i < 589824)      { src = vw;  off = i - 327680; }
    else                      { src = tw;  off = i - 589824; }
    o[i] = (_Float16)src[off];
}

// ---------------- transpose + cast x -> XT[b][n][c] (entry only) ----------------
__global__ __launch_bounds__(256) void k_fuse_t(const float* __restrict__ in,
        _Float16* __restrict__ XT) {
    __shared__ _Float16 Tt[64][72];
    const int b = blockIdx.z, c0 = blockIdx.y * 64, n0 = blockIdx.x * 64;
    const int t = threadIdx.x;
    const int cl = t >> 2, ns = (t & 3) * 16;
    const float* ip = in + ((size_t)(b * Cch + c0 + cl) * Npt) + n0 + ns;
    #pragma unroll
    for (int g = 0; g < 4; ++g) {
        float4 v = *(const float4*)(ip + g * 4);
        Tt[ns + g * 4 + 0][cl] = (_Float16)v.x;
        Tt[ns + g * 4 + 1][cl] = (_Float16)v.y;
        Tt[ns + g * 4 + 2][cl] = (_Float16)v.z;
        Tt[ns + g * 4 + 3][cl] = (_Float16)v.w;
    }
    __syncthreads();
    int nl = t >> 2, cs = (t & 3) * 16;
    _Float16* op = XT + ((size_t)(b * Npt + n0 + nl) * Cch) + c0 + cs;
    #pragma unroll
    for (int g = 0; g < 4; ++g)
        *(f16x4*)(op + g * 4) = *(f16x4*)&Tt[nl][cs + g * 4];
}

// ---------------- MFMA GEMM (fp32 out) + fused BN partial-stat atomics ----------------
__global__ __launch_bounds__(256) void k_gemm_mfma(const _Float16* __restrict__ Wb,
        const _Float16* __restrict__ XT, const float* __restrict__ bias,
        float* __restrict__ Yf, float* __restrict__ bnacc) {
    __shared__ float EpF[64][68];
    const int b = blockIdx.z, o0 = blockIdx.y * 64, n0 = blockIdx.x * 64;
    const int tid = threadIdx.x, w = tid >> 6, quad = (tid >> 4) & 3, tx = tid & 15;
    const _Float16* Arow = Wb + (o0 + w * 16 + tx) * Cch + quad * 8;
    const _Float16* Brow = XT + ((size_t)(b * Npt + n0 + tx) * Cch) + quad * 8;
    f32x4 acc[4];
    #pragma unroll
    for (int s = 0; s < 4; ++s) acc[s] = (f32x4){0.f, 0.f, 0.f, 0.f};
    for (int k0 = 0; k0 < Cch; k0 += 32) {
        f16x8 a = *(const f16x8*)(Arow + k0);
        #pragma unroll
        for (int s = 0; s < 4; ++s) {
            f16x8 bb = *(const f16x8*)(Brow + s * 16 * Cch + k0);
            acc[s] = __builtin_amdgcn_mfma_f32_16x16x32_f16(a, bb, acc[s], 0, 0, 0);
        }
    }
    float bv[4];
    {
        int ob = o0 + w * 16 + quad * 4;
        if (bias) { bv[0] = bias[ob]; bv[1] = bias[ob + 1]; bv[2] = bias[ob + 2]; bv[3] = bias[ob + 3]; }
        else bv[0] = bv[1] = bv[2] = bv[3] = 0.f;
    }
    #pragma unroll
    for (int s = 0; s < 4; ++s) {
        int ol = w * 16 + quad * 4, nl = s * 16 + tx;
        EpF[ol + 0][nl] = acc[s][0] + bv[0];
        EpF[ol + 1][nl] = acc[s][1] + bv[1];
        EpF[ol + 2][nl] = acc[s][2] + bv[2];
        EpF[ol + 3][nl] = acc[s][3] + bv[3];
    }
    __syncthreads();
    int row = tid >> 2, seg = (tid & 3) * 16;
    float* yp = Yf + ((size_t)(b * Cch + o0 + row) * Npt) + n0 + seg;
    float s1 = 0.f, s2 = 0.f;
    #pragma unroll
    for (int g = 0; g < 4; ++g) {
        float4 v = *(float4*)&EpF[row][seg + g * 4];
        *(float4*)(yp + g * 4) = v;
        s1 += v.x + v.y + v.z + v.w;
        s2 += v.x * v.x + v.y * v.y + v.z * v.z + v.w * v.w;
    }
    s1 += __shfl_xor(s1, 1); s2 += __shfl_xor(s2, 1);
    s1 += __shfl_xor(s1, 2); s2 += __shfl_xor(s2, 2);
    if ((tid & 3) == 0) {
        atomicAdd(&bnacc[o0 + row], s1);
        atomicAdd(&bnacc[256 + o0 + row], s2);
    }
}

// ---------------- fused qk + v GEMM: y<4 -> Qg/Kt (swizzled), y>=4 -> Vb fp16 ----------------
__global__ __launch_bounds__(256) void k_gemm_qkv(const _Float16* __restrict__ Wqk,
        const _Float16* __restrict__ Wv, const _Float16* __restrict__ XT,
        const float* __restrict__ vbias, _Float16* __restrict__ Vb,
        _Float16* __restrict__ Qg, _Float16* __restrict__ Kt) {
    __shared__ _Float16 EpB[64][72];
    const int b = blockIdx.z, y = blockIdx.y, n0 = blockIdx.x * 64;
    const int isV = (y >= 4);
    const int o0 = (isV ? (y - 4) : y) * 64;
    const _Float16* Wb = isV ? Wv : Wqk;
    const int tid = threadIdx.x, w = tid >> 6, quad = (tid >> 4) & 3, tx = tid & 15;
    const _Float16* Arow = Wb + (o0 + w * 16 + tx) * Cch + quad * 8;
    const _Float16* Brow = XT + ((size_t)(b * Npt + n0 + tx) * Cch) + quad * 8;
    f32x4 acc[4];
    #pragma unroll
    for (int s = 0; s < 4; ++s) acc[s] = (f32x4){0.f, 0.f, 0.f, 0.f};
    for (int k0 = 0; k0 < Cch; k0 += 32) {
        f16x8 a = *(const f16x8*)(Arow + k0);
        #pragma unroll
        for (int s = 0; s < 4; ++s) {
            f16x8 bb = *(const f16x8*)(Brow + s * 16 * Cch + k0);
            acc[s] = __builtin_amdgcn_mfma_f32_16x16x32_f16(a, bb, acc[s], 0, 0, 0);
        }
    }
    if (!isV) {
        const int cch = (w << 1) + (quad >> 1);
        const int hof = (quad & 1) * 4;
        #pragma unroll
        for (int s = 0; s < 4; ++s) {
            int ng = n0 + s * 16 + tx;
            f16x4 pk;
            pk[0] = (_Float16)acc[s][0]; pk[1] = (_Float16)acc[s][1];
            pk[2] = (_Float16)acc[s][2]; pk[3] = (_Float16)acc[s][3];
            int rK = ng & 63, jt = ng >> 6;
            size_t ka = ((size_t)((b * Hh + (o0 >> 6)) * 32 + jt) << 12)
                      + rK * 64 + ((cch ^ (rK & 7)) * 8) + hof;
            *(f16x4*)&Kt[ka] = pk;
            int iQ = ((ng & 511) << 2) + (o0 >> 6);
            int rQ = iQ & 63, it = iQ >> 6;
            size_t qa = ((size_t)((b * Hh + (ng >> 9)) * 32 + it) << 12)
                      + rQ * 64 + ((cch ^ (rQ & 7)) * 8) + hof;
            *(f16x4*)&Qg[qa] = pk;
        }
        return;
    }
    float bv[4];
    {
        int ob = o0 + w * 16 + quad * 4;
        bv[0] = vbias[ob]; bv[1] = vbias[ob + 1]; bv[2] = vbias[ob + 2]; bv[3] = vbias[ob + 3];
    }
    #pragma unroll
    for (int s = 0; s < 4; ++s) {
        int ol = w * 16 + quad * 4, nl = s * 16 + tx;
        EpB[ol + 0][nl] = (_Float16)(acc[s][0] + bv[0]);
        EpB[ol + 1][nl] = (_Float16)(acc[s][1] + bv[1]);
        EpB[ol + 2][nl] = (_Float16)(acc[s][2] + bv[2]);
        EpB[ol + 3][nl] = (_Float16)(acc[s][3] + bv[3]);
    }
    __syncthreads();
    int row = tid >> 2, seg = (tid & 3) * 16;
    _Float16* yp = Vb + ((size_t)(b * Cch + o0 + row) * Npt) + n0 + seg;
    #pragma unroll
    for (int g = 0; g < 4; ++g)
        *(f16x4*)(yp + g * 4) = *(f16x4*)&EpB[row][seg + g * 4];
}

// ---------------- attention pass A: 128 i-rows/block, per-lane online (m2,l) ----------------
// 1-D grid 1024; XCD-aware remap: bh=(flat&7)*2+((flat>>3)&1) so each bh's Q/K live in
// ONE XCD's L2 (per-XCD L2s are not shared; default round-robin thrashed HBM 2-3x).
__global__ __launch_bounds__(256) void k_attn_A(const _Float16* __restrict__ Qg,
        const _Float16* __restrict__ Kt, float* __restrict__ mP, float* __restrict__ lP) {
    __shared__ _Float16 Ksh[2][4096];
    const int flat = blockIdx.x;
    const int bh = (flat & 7) * 2 + ((flat >> 3) & 1);
    const int rest = flat >> 4;              // 0..63
    const int i0 = (rest & 15) * 128;
    const int jc = rest >> 4;                // 0..3
    const int tid = threadIdx.x, w = tid >> 6, q = (tid >> 4) & 3, tx = tid & 15;
    const int lane = tid & 63;
    const int sx = tx & 7;
    f16x8 qa[2][2];
    #pragma unroll
    for (int g = 0; g < 2; ++g) {
        const _Float16* Qtile = Qg + ((size_t)(bh * 32 + ((i0 + g * 64) >> 6)) << 12);
        int r = w * 16 + tx;
        qa[g][0] = *(const f16x8*)(Qtile + r * 64 + (q ^ sx) * 8);
        qa[g][1] = *(const f16x8*)(Qtile + r * 64 + ((q + 4) ^ sx) * 8);
    }
    const _Float16* Kbase = Kt + ((size_t)(bh * 32) << 12);
    const int jt0 = jc * 8;
    {
        const _Float16* g = Kbase + ((size_t)jt0 << 12) + (w * 2) * 512 + lane * 8;
        gld16(g,       &Ksh[0][(w * 2 + 0) * 512]);
        gld16(g + 512, &Ksh[0][(w * 2 + 1) * 512]);
    }
    __syncthreads();
    float m2[2][4], l[2][4];
    #pragma unroll
    for (int g = 0; g < 2; ++g)
        #pragma unroll
        for (int r = 0; r < 4; ++r) { m2[g][r] = -1e30f; l[g][r] = 0.f; }
    for (int t = 0; t < 8; ++t) {
        if (t < 7) {
            const _Float16* g = Kbase + ((size_t)(jt0 + t + 1) << 12) + (w * 2) * 512 + lane * 8;
            gld16(g,       &Ksh[(t + 1) & 1][(w * 2 + 0) * 512]);
            gld16(g + 512, &Ksh[(t + 1) & 1][(w * 2 + 1) * 512]);
        }
        const _Float16* kbuf = Ksh[t & 1];
        f32x4 e[2][4];
        #pragma unroll
        for (int s = 0; s < 4; ++s) {
            int r = s * 16 + tx;
            f16x8 kb0 = *(const f16x8*)(kbuf + r * 64 + (q ^ sx) * 8);
            f16x8 kb1 = *(const f16x8*)(kbuf + r * 64 + ((q + 4) ^ sx) * 8);
            #pragma unroll
            for (int g = 0; g < 2; ++g) {
                f32x4 z = (f32x4){0.f, 0.f, 0.f, 0.f};
                z = __builtin_amdgcn_mfma_f32_16x16x32_f16(qa[g][0], kb0, z, 0, 0, 0);
                e[g][s] = __builtin_amdgcn_mfma_f32_16x16x32_f16(qa[g][1], kb1, z, 0, 0, 0);
            }
        }
        #pragma unroll
        for (int g = 0; g < 2; ++g)
            #pragma unroll
            for (int r = 0; r < 4; ++r) {
                float e0 = e[g][0][r] * L2E, e1 = e[g][1][r] * L2E;
                float e2 = e[g][2][r] * L2E, e3 = e[g][3][r] * L2E;
                float lm = fmaxf(fmaxf(e0, e1), fmaxf(e2, e3));
                float nm = fmaxf(m2[g][r], lm);
                l[g][r] = l[g][r] * fexp2(m2[g][r] - nm)
                        + fexp2(e0 - nm) + fexp2(e1 - nm) + fexp2(e2 - nm) + fexp2(e3 - nm);
                m2[g][r] = nm;
            }
        __syncthreads();
    }
    #pragma unroll
    for (int g = 0; g < 2; ++g)
        #pragma unroll
        for (int r = 0; r < 4; ++r) {
            float mm = m2[g][r], ll = l[g][r];
            #pragma unroll
            for (int off = 1; off < 16; off <<= 1) {
                float om = __shfl_xor(mm, off), ol = __shfl_xor(ll, off);
                float nm = fmaxf(mm, om);
                ll = ll * fexp2(mm - nm) + ol * fexp2(om - nm);
                mm = nm;
            }
            if (tx == 0) {
                int idx = bh * Npt + i0 + g * 64 + w * 16 + q * 4 + r;
                mP[jc * NROW + idx] = mm;
                lP[jc * NROW + idx] = ll;
            }
        }
}

// ---------------- combine chunk (m2,l) partials -> rowm2, rowli2 = L2E/l ----------------
__global__ void k_mlcomb(const float* __restrict__ mP, const float* __restrict__ lP,
                         float* __restrict__ rowm2, float* __restrict__ rowli2) {
    int row = blockIdx.x * 256 + threadIdx.x;    // NROW threads
    float m0 = mP[row], m1 = mP[NROW + row], m2 = mP[2 * NROW + row], m3 = mP[3 * NROW + row];
    float m = fmaxf(fmaxf(m0, m1), fmaxf(m2, m3));
    float l = lP[row] * fexp2(m0 - m) + lP[NROW + row] * fexp2(m1 - m)
            + lP[2 * NROW + row] * fexp2(m2 - m) + lP[3 * NROW + row] * fexp2(m3 - m);
    rowm2[row] = m;
    rowli2[row] = L2E / l;
}

// ---------------- attention pass B: wave-private 512-row i-chunks, ZERO barriers ----------------
// 1-D grid 512; XCD-aware remap (same scheme as pass A): bh's Q/K/V pinned to one XCD L2.
__global__ __launch_bounds__(256) void k_attn_B(const _Float16* __restrict__ Qg,
        const _Float16* __restrict__ Kt, const _Float16* __restrict__ Vb,
        const float* __restrict__ rowm2, const float* __restrict__ rowli2,
        _Float16* __restrict__ Tp, float* __restrict__ Sp) {
    __shared__ _Float16 AtT[4][4096];     // per-wave 8KB swizzled P scratch
    const int flat = blockIdx.x;
    const int bh = (flat & 7) * 2 + ((flat >> 3) & 1);
    const int j0 = (flat >> 4) * 64;
    const int b = bh >> 2, hd = bh & 3;
    const int tid = threadIdx.x, w = tid >> 6, q = (tid >> 4) & 3, tx = tid & 15;
    const int sx = tx & 7;
    f16x8 kb[4][2];
    const _Float16* Ktile = Kt + ((size_t)(bh * 32 + (j0 >> 6)) << 12);
    #pragma unroll
    for (int nt = 0; nt < 4; ++nt) {
        int r = nt * 16 + tx;
        kb[nt][0] = *(const f16x8*)(Ktile + r * 64 + (q ^ sx) * 8);
        kb[nt][1] = *(const f16x8*)(Ktile + r * 64 + ((q + 4) ^ sx) * 8);
    }
    f32x4 Tacc[4][4];
    #pragma unroll
    for (int mt = 0; mt < 4; ++mt)
        #pragma unroll
        for (int nt = 0; nt < 4; ++nt) Tacc[mt][nt] = (f32x4){0.f, 0.f, 0.f, 0.f};
    float scS[4] = {0.f, 0.f, 0.f, 0.f};
    _Float16* myAt = AtT[w];
    const _Float16* vbase = Vb + (size_t)(b * Cch + hd * 64) * Npt;
    const float* m2b = rowm2 + bh * Npt;
    const float* lib = rowli2 + bh * Npt;
    for (int it = 0; it < 8; ++it) {
        const int i0 = w * 512 + it * 64;
        const _Float16* Qtile = Qg + ((size_t)(bh * 32 + (i0 >> 6)) << 12);
        #pragma unroll
        for (int mt = 0; mt < 4; ++mt) {
            int r = mt * 16 + tx;
            f16x8 qa0 = *(const f16x8*)(Qtile + r * 64 + (q ^ sx) * 8);
            f16x8 qa1 = *(const f16x8*)(Qtile + r * 64 + ((q + 4) ^ sx) * 8);
            float4 m2v = *(const float4*)(m2b + i0 + mt * 16 + q * 4);
            float4 liv = *(const float4*)(lib + i0 + mt * 16 + q * 4);
            #pragma unroll
            for (int nt = 0; nt < 4; ++nt) {
                f32x4 z = (f32x4){0.f, 0.f, 0.f, 0.f};
                z = __builtin_amdgcn_mfma_f32_16x16x32_f16(qa0, kb[nt][0], z, 0, 0, 0);
                z = __builtin_amdgcn_mfma_f32_16x16x32_f16(qa1, kb[nt][1], z, 0, 0, 0);
                float a0 = fexp2(fexp2(__builtin_fmaf(z[0], L2E, -m2v.x)) * liv.x);
                float a1 = fexp2(fexp2(__builtin_fmaf(z[1], L2E, -m2v.y)) * liv.y);
                float a2 = fexp2(fexp2(__builtin_fmaf(z[2], L2E, -m2v.z)) * liv.z);
                float a3 = fexp2(fexp2(__builtin_fmaf(z[3], L2E, -m2v.w)) * liv.w);
                scS[nt] += a0 + a1 + a2 + a3;
                f16x4 pk;
                pk[0] = (_Float16)a0; pk[1] = (_Float16)a1;
                pk[2] = (_Float16)a2; pk[3] = (_Float16)a3;
                *(f16x4*)&myAt[(nt * 16 + tx) * 64 + ((2 * mt + (q >> 1)) ^ sx) * 8 + (q & 1) * 4] = pk;
            }
        }
        f16x8 pb[4][2], va[4][2];
        #pragma unroll
        for (int nt = 0; nt < 4; ++nt) {
            int r = nt * 16 + tx;
            pb[nt][0] = *(const f16x8*)&myAt[r * 64 + (q ^ sx) * 8];
            pb[nt][1] = *(const f16x8*)&myAt[r * 64 + ((q + 4) ^ sx) * 8];
        }
        #pragma unroll
        for (int mt = 0; mt < 4; ++mt) {
            const _Float16* vp = vbase + (size_t)(mt * 16 + tx) * Npt + i0 + q * 8;
            va[mt][0] = *(const f16x8*)(vp);
            va[mt][1] = *(const f16x8*)(vp + 32);
        }
        #pragma unroll
        for (int mt = 0; mt < 4; ++mt)
            #pragma unroll
            for (int nt = 0; nt < 4; ++nt) {
                Tacc[mt][nt] = __builtin_amdgcn_mfma_f32_16x16x32_f16(va[mt][0], pb[nt][0], Tacc[mt][nt], 0, 0, 0);
                Tacc[mt][nt] = __builtin_amdgcn_mfma_f32_16x16x32_f16(va[mt][1], pb[nt][1], Tacc[mt][nt], 0, 0, 0);
            }
    }
    const size_t NE = (size_t)Bsz * Cch * Npt;
    #pragma unroll
    for (int mt = 0; mt < 4; ++mt)
        #pragma unroll
        for (int nt = 0; nt < 4; ++nt) {
            int d = hd * 64 + mt * 16 + q * 4;
            int jg = j0 + nt * 16 + tx;
            _Float16* tp = Tp + (size_t)w * NE + (size_t)(b * Cch + d) * Npt + jg;
            tp[0 * Npt] = (_Float16)Tacc[mt][nt][0];
            tp[1 * Npt] = (_Float16)Tacc[mt][nt][1];
            tp[2 * Npt] = (_Float16)Tacc[mt][nt][2];
            tp[3 * Npt] = (_Float16)Tacc[mt][nt][3];
        }
    #pragma unroll
    for (int nt = 0; nt < 4; ++nt) {
        float s = scS[nt];
        s += __shfl_xor(s, 16);
        s += __shfl_xor(s, 32);
        if (q == 0) Sp[(size_t)w * NROW + bh * Npt + j0 + nt * 16 + tx] = s;
    }
}

// ---------------- reduce T/S partials (4), u = h - T/S, transpose+cast -> XT ----------------
__global__ __launch_bounds__(256) void k_redT_fuse(const float* __restrict__ h,
        const _Float16* __restrict__ Tp, const float* __restrict__ Sp,
        _Float16* __restrict__ XT) {
    __shared__ _Float16 Tt[64][72];
    __shared__ float rsL[64];
    const int b = blockIdx.z, c0 = blockIdx.y * 64, n0 = blockIdx.x * 64;
    const int t = threadIdx.x;
    const int bh = b * Hh + (c0 >> 6);
    if (t < 64) {
        float s = 0.f;
        #pragma unroll
        for (int ic = 0; ic < NIC; ++ic) s += Sp[(size_t)ic * NROW + bh * Npt + n0 + t];
        rsL[t] = 1.f / s;
    }
    __syncthreads();
    const int cl = t >> 2, ns = (t & 3) * 16;
    const size_t NE = (size_t)Bsz * Cch * Npt;
    const size_t rowoff = ((size_t)(b * Cch + c0 + cl) * Npt) + n0 + ns;
    float tv[16];
    #pragma unroll
    for (int e = 0; e < 16; ++e) tv[e] = 0.f;
    #pragma unroll
    for (int ic = 0; ic < NIC; ++ic) {
        const _Float16* qq = Tp + (size_t)ic * NE + rowoff;
        #pragma unroll
        for (int g = 0; g < 2; ++g) {
            f16x8 vv = *(const f16x8*)(qq + g * 8);
            #pragma unroll
            for (int e = 0; e < 8; ++e) tv[g * 8 + e] += (float)vv[e];
        }
    }
    const float* hp = h + rowoff;
    #pragma unroll
    for (int g = 0; g < 4; ++g) {
        float4 hv = *(const float4*)(hp + g * 4);
        Tt[ns + g * 4 + 0][cl] = (_Float16)(hv.x - tv[g * 4 + 0] * rsL[ns + g * 4 + 0]);
        Tt[ns + g * 4 + 1][cl] = (_Float16)(hv.y - tv[g * 4 + 1] * rsL[ns + g * 4 + 1]);
        Tt[ns + g * 4 + 2][cl] = (_Float16)(hv.z - tv[g * 4 + 2] * rsL[ns + g * 4 + 2]);
        Tt[ns + g * 4 + 3][cl] = (_Float16)(hv.w - tv[g * 4 + 3] * rsL[ns + g * 4 + 3]);
    }
    __syncthreads();
    int nl = t >> 2, cs = (t & 3) * 16;
    _Float16* op = XT + ((size_t)(b * Npt + n0 + nl) * Cch) + c0 + cs;
    #pragma unroll
    for (int g = 0; g < 4; ++g)
        *(f16x4*)(op + g * 4) = *(f16x4*)&Tt[nl][cs + g * 4];
}

// ---- fused BN(from atomically-accumulated stats) + relu + residual + out + transpose -> XT ----
__global__ __launch_bounds__(256) void k_bn_fuse(const float* __restrict__ t,
        const float* __restrict__ bnacc,
        const float* __restrict__ g, const float* __restrict__ bt,
        const float* __restrict__ emb, const float* __restrict__ resid,
        float* __restrict__ hout, float* __restrict__ out, _Float16* __restrict__ XT,
        int layer) {
    __shared__ _Float16 Tt[64][72];
    const int b = blockIdx.z, c0 = blockIdx.y * 64, n0 = blockIdx.x * 64;
    const int tt = threadIdx.x;
    const int cl = tt >> 2, ns = (tt & 3) * 16;
    const int c = c0 + cl;
    const float mn = bnacc[c] * (1.f / BN_CNT);
    const float var = bnacc[256 + c] * (1.f / BN_CNT) - mn * mn;
    const float is = rsqrtf(var + EPSV);
    const float gg = g[c], bb = bt[c];
    const size_t rowoff = ((size_t)(b * Cch + c) * Npt) + n0 + ns;
    const float* tp = t + rowoff;
    const float* ep = emb + rowoff;
    const float* rp = resid ? resid + rowoff : nullptr;
    float* hp = hout + rowoff;
    float* op = out ? out + (size_t)b * (NL * Cch * Npt) + (size_t)(layer * Cch + c) * Npt + n0 + ns
                    : nullptr;
    #pragma unroll
    for (int gi = 0; gi < 4; ++gi) {
        float4 v = *(const float4*)(tp + gi * 4);
        float4 y;
        y.x = fmaxf(gg * (v.x - mn) * is + bb, 0.f);
        y.y = fmaxf(gg * (v.y - mn) * is + bb, 0.f);
        y.z = fmaxf(gg * (v.z - mn) * is + bb, 0.f);
        y.w = fmaxf(gg * (v.w - mn) * is + bb, 0.f);
        if (rp) {
            float4 r = *(const float4*)(rp + gi * 4);
            y.x += r.x; y.y += r.y; y.z += r.z; y.w += r.w;
        }
        *(float4*)(hp + gi * 4) = y;
        if (op) *(float4*)(op + gi * 4) = y;
        float4 e = *(const float4*)(ep + gi * 4);
        Tt[ns + gi * 4 + 0][cl] = (_Float16)(y.x + e.x);
        Tt[ns + gi * 4 + 1][cl] = (_Float16)(y.y + e.y);
        Tt[ns + gi * 4 + 2][cl] = (_Float16)(y.z + e.z);
        Tt[ns + gi * 4 + 3][cl] = (_Float16)(y.w + e.w);
    }
    __syncthreads();
    int nl = tt >> 2, cs = (tt & 3) * 16;
    _Float16* xp = XT + ((size_t)(b * Npt + n0 + nl) * Cch) + c0 + cs;
    #pragma unroll
    for (int gi = 0; gi < 4; ++gi)
        *(f16x4*)(xp + gi * 4) = *(f16x4*)&Tt[nl][cs + gi * 4];
}

extern "C" void kernel_launch(void* const* d_in, const int* in_sizes, int n_in,
                              void* d_out, int out_size, void* d_ws, size_t ws_size,
                              hipStream_t stream) {
    (void)in_sizes; (void)n_in; (void)out_size; (void)ws_size;
    const float* x    = (const float*)d_in[0];
    const float* xyz  = (const float*)d_in[1];
    const float* c1w  = (const float*)d_in[2];
    const float* posw = (const float*)d_in[3];
    const float* posb = (const float*)d_in[4];
    const float* bn1g = (const float*)d_in[5];
    const float* bn1b = (const float*)d_in[6];
    const float* qkw  = (const float*)d_in[7];
    const float* vw   = (const float*)d_in[8];
    const float* vb   = (const float*)d_in[9];
    const float* tw   = (const float*)d_in[10];
    const float* tb   = (const float*)d_in[11];
    const float* bng  = (const float*)d_in[12];
    const float* bnb  = (const float*)d_in[13];
    float* out = (float*)d_out;

    const size_t NE = (size_t)Bsz * Cch * Npt;   // 2,097,152
    char* W = (char*)d_ws;
    float* emb   = (float*)W;                 W += NE * 4;
    float* h     = (float*)W;                 W += NE * 4;
    float* vbuf  = (float*)W;                 W += NE * 4;   // fp32 conv outputs
    _Float16* Tp = (_Float16*)W;              W += (size_t)NIC * NE * 2;   // 4 fp16 partials
    _Float16* XT = (_Float16*)W;              W += NE * 2;
    _Float16* Qg = (_Float16*)W;              W += NE * 2;
    _Float16* Kt = (_Float16*)W;              W += NE * 2;
    _Float16* Vb = (_Float16*)W;              W += NE * 2;
    _Float16* wbf = (_Float16*)W;             W += 851968 * 2;
    float* rowm2 = (float*)W;                 W += NROW * 4;
    float* rowli2 = (float*)W;                W += NROW * 4;
    float* mP    = (float*)W;                 W += 4 * NROW * 4;
    float* lP    = (float*)W;                 W += 4 * NROW * 4;
    float* Sp    = (float*)W;                 W += NIC * NROW * 4;
    float* bnacc = (float*)W;                 W += 5 * 512 * 4;   // 5 slots x (sum,sum2)

    dim3 blk(256);
    dim3 g4(Npt / 64, Cch / 64, Bsz);    // 32,4,4
    dim3 gQKV(Npt / 64, 8, Bsz);         // 32,8,4 — fused qk+v
    int ew = (int)(NE / 256);

    k_castw<<<3328, blk, 0, stream>>>(c1w, qkw, vw, tw, wbf, bnacc);
    k_xyz_emb<<<ew, blk, 0, stream>>>(xyz, posw, posb, emb);

    // h0 = relu(bn1(conv1_w @ x)); XT = transpose(h0 + emb)
    k_fuse_t<<<g4, blk, 0, stream>>>(x, XT);
    k_gemm_mfma<<<g4, blk, 0, stream>>>(wbf, XT, nullptr, vbuf, bnacc);
    k_bn_fuse<<<g4, blk, 0, stream>>>(vbuf, bnacc, bn1g, bn1b, emb, nullptr,
                                      h, nullptr, XT, 0);

    for (int L = 0; L < NL; ++L) {
        const _Float16* qkL = wbf + 65536 + (size_t)L * 65536;
        const _Float16* vL  = wbf + 327680 + (size_t)L * 65536;
        const _Float16* tL  = wbf + 589824 + (size_t)L * 65536;
        float* accL = bnacc + (1 + L) * 512;
        k_gemm_qkv<<<gQKV, blk, 0, stream>>>(qkL, vL, XT, vb + L * Cch, Vb, Qg, Kt);
        k_attn_A<<<1024, blk, 0, stream>>>(Qg, Kt, mP, lP);
        k_mlcomb<<<NROW / 256, blk, 0, stream>>>(mP, lP, rowm2, rowli2);
        k_attn_B<<<512, blk, 0, stream>>>(Qg, Kt, Vb, rowm2, rowli2, Tp, Sp);
        k_redT_fuse<<<g4, blk, 0, stream>>>(h, Tp, Sp, XT);
        k_gemm_mfma<<<g4, blk, 0, stream>>>(tL, XT, tb + L * Cch, vbuf, accL);
        k_bn_fuse<<<g4, blk, 0, stream>>>(vbuf, accL, bng + L * Cch, bnb + L * Cch,
                                          emb, h, h, out, XT, L);
    }
}